// Round 1
// baseline (83384.338 us; speedup 1.0000x reference)
//
#include <hip/hip_runtime.h>
#include <hip/hip_bf16.h>

typedef unsigned int  u32;
typedef unsigned short u16;
typedef __attribute__((ext_vector_type(8))) short short8;
typedef __attribute__((ext_vector_type(4))) float f32x4;

#define MFMA(a,b,c) __builtin_amdgcn_mfma_f32_16x16x32_bf16(a,b,c,0,0,0)

#define NWG    256
#define Bz     64
#define KD0    1448   /* 416 + 1024 + 8 pad */
#define KD1    2056   /* 2048 + 8 pad */
#define KEMB   520    /* 512 + 8 pad */
#define KPROJ  1032   /* 1024 + 8 pad */

/* workspace layout (bytes) */
#define WS_FLAGS 0
#define WS_LAT   1024
#define WS_NOTE  (WS_LAT + 64*512*2)
#define WS_HD0   (WS_NOTE + 2*64*416*2)
#define WS_HD1   (WS_HD0 + 2*64*1024*2)
#define WS_HC0   (WS_HD1 + 2*64*1024*2)
#define WS_HC1   (WS_HC0 + 2*64*1024*2)
#define WS_EMB   (WS_HC1 + 2*64*1024*2)
#define WS_END   (WS_EMB + 16*64*512*2)

/* LDS layout (bytes) */
#define L_GSC   0                       /* 64*33 f32 = 8448 */
#define L_GC0X  8448                    /* 64*17 f32 = 4352 */
#define L_CC0   12800                   /* 4*64 f32 */
#define L_CC1   13824
#define L_BC1   14848                   /* 16 f32 */
#define L_ROLE  14912
/* d0 role */
#define L_WD0   L_ROLE                          /* 32*KD0*2 = 92672 */
#define L_WEMB  (L_ROLE + 32*KD0*2)             /* 32*KEMB*2 = 33280 */
#define L_G0E   (L_WEMB + 32*KEMB*2)            /* 64*33 f32 = 8448 */
#define L_CST0  (L_G0E + 8448)                  /* 8*64 f32 */
#define L_BD0   (L_CST0 + 2048)                 /* 32 f32 */
/* d1 role */
#define L_WD1   L_ROLE                          /* 32*KD1*2 = 131584 */
#define L_CST1  (L_ROLE + 32*KD1*2)
#define L_BD1   (L_CST1 + 2048)
#define L_WPJ   (L_BD1 + 128)                   /* 7*KPROJ*2 = 14448 */
#define L_BPJ   (L_WPJ + 7*KPROJ*2)             /* 7 f32 -> end 163148 < 163840 */

#define LDS_BYTES 163840

__device__ __forceinline__ u16 f2bf(float f){
  u32 u = __float_as_uint(f);
  u32 r = (u + 0x7FFFu + ((u >> 16) & 1u)) >> 16;
  return (u16)r;
}
__device__ __forceinline__ float sigm(float x){ return 1.f/(1.f + __expf(-x)); }
__device__ __forceinline__ float tanh_(float x){
  float e = __expf(-2.f*fabsf(x));
  float t = (1.f - e)/(1.f + e);
  return x < 0.f ? -t : t;
}
__device__ __forceinline__ short8 ldw8(const float* p0){
  short8 r;
#pragma unroll
  for (int j = 0; j < 8; ++j) r[j] = (short)f2bf(p0[j]);
  return r;
}

/* contention-free grid barrier: per-WG flag + min-scan by wave 0 */
__device__ __forceinline__ void gbar(u32* flags, int wg, u32 ep){
  __threadfence();
  __syncthreads();
  if (threadIdx.x < 64){
    const int lane = threadIdx.x;
    if (lane == 0)
      __hip_atomic_store(&flags[wg], ep, __ATOMIC_RELEASE, __HIP_MEMORY_SCOPE_AGENT);
    for (;;){
      u32 m = 0xFFFFFFFFu;
#pragma unroll
      for (int j = 0; j < 4; ++j){
        u32 v = __hip_atomic_load(&flags[lane*4 + j], __ATOMIC_RELAXED, __HIP_MEMORY_SCOPE_AGENT);
        m = v < m ? v : m;
      }
#pragma unroll
      for (int off = 32; off; off >>= 1){
        u32 o = (u32)__shfl_xor((int)m, off, 64);
        m = o < m ? o : m;
      }
      if (m >= ep) break;
      __builtin_amdgcn_s_sleep(2);
    }
  }
  __syncthreads();
  __builtin_amdgcn_fence(__ATOMIC_ACQUIRE, "agent");
}

struct Params {
  const float *latent, *h0_dec, *c0_dec;
  const float *Wih_c0, *Whh_c0, *bih_c0, *bhh_c0;
  const float *Wih_c1, *Whh_c1, *bih_c1, *bhh_c1;
  const float *Wco, *bco;
  const float *Wih_d0, *Whh_d0, *bih_d0, *bhh_d0;
  const float *Wih_d1, *Whh_d1, *bih_d1, *bhh_d1;
  const float *Wdo, *bdo;
  float* out;
  char* ws;
};

/* [64 x 32cols] = x @ W^T, W in LDS row-major [32][ldw], x bf16 in global.
   waves: M2N2 (mh=wid&1 -> batch half, nh=wid>>1 -> 16-col half). */
__device__ __forceinline__ void stage_cell32(
    const u16* W, int ldw,
    const u16* xa, int lda, int na,
    const u16* xb, int ldb, int nb, int kwb,
    float* g_sc, int lane, int wid)
{
  const int mh = wid & 1, nh = wid >> 1;
  const int ao = (lane >> 4) << 3;
  const u16* Wn = W + (size_t)(nh*16 + (lane & 15))*ldw + ao;
  f32x4 acc0 = {0.f,0.f,0.f,0.f}, acc1 = {0.f,0.f,0.f,0.f};
  const u16* xa0 = xa + (size_t)(mh*32 + (lane & 15))*lda + ao;
  const u16* xa1 = xa0 + (size_t)16*lda;
#pragma unroll 4
  for (int kc = 0; kc < na; ++kc){
    short8 bfr = *(const short8*)(Wn + kc*32);
    acc0 = MFMA(*(const short8*)(xa0 + kc*32), bfr, acc0);
    acc1 = MFMA(*(const short8*)(xa1 + kc*32), bfr, acc1);
  }
  const u16* Wn2 = Wn + kwb;
  const u16* xb0 = xb + (size_t)(mh*32 + (lane & 15))*ldb + ao;
  const u16* xb1 = xb0 + (size_t)16*ldb;
#pragma unroll 4
  for (int kc = 0; kc < nb; ++kc){
    short8 bfr = *(const short8*)(Wn2 + kc*32);
    acc0 = MFMA(*(const short8*)(xb0 + kc*32), bfr, acc0);
    acc1 = MFMA(*(const short8*)(xb1 + kc*32), bfr, acc1);
  }
  const int col = nh*16 + (lane & 15);
  const int r0  = mh*32 + ((lane >> 4) << 2);
#pragma unroll
  for (int q = 0; q < 4; ++q){
    g_sc[(r0 + q)*33 + col]      = acc0[q];
    g_sc[(r0 + 16 + q)*33 + col] = acc1[q];
  }
}

/* LSTM pointwise over this CU's 8 hidden units (cols: [i 0..7 | f 8..15 | g 16..23 | o 24..31]) */
__device__ __forceinline__ void cell_pointwise(
    const float* g_sc, const float* gadd, const float* bias,
    float* cst, u16* hnext, int u0, int tid)
{
  const int ul = tid >> 5;          /* 0..7 */
  const int bb = tid & 31;
#pragma unroll
  for (int half = 0; half < 2; ++half){
    const int b = bb + half*32;
    float gi = g_sc[b*33 + ul];
    float gf = g_sc[b*33 + 8 + ul];
    float gg = g_sc[b*33 + 16 + ul];
    float go = g_sc[b*33 + 24 + ul];
    if (gadd){
      gi += gadd[b*33 + ul];      gf += gadd[b*33 + 8 + ul];
      gg += gadd[b*33 + 16 + ul]; go += gadd[b*33 + 24 + ul];
    }
    if (bias){
      gi += bias[ul]; gf += bias[8 + ul]; gg += bias[16 + ul]; go += bias[24 + ul];
    }
    float c = sigm(gf)*cst[ul*64 + b] + sigm(gi)*tanh_(gg);
    const float h = sigm(go)*tanh_(c);
    cst[ul*64 + b] = c;
    hnext[(size_t)b*1024 + u0 + ul] = f2bf(h);
  }
}

/* conductor LSTM stage, M4N1, weights streamed from global fp32.
   This CU owns 4 units: rows r=0..15 -> gate (r>>2), unit ubase+(r&3). */
__device__ __forceinline__ void cond_stage(
    const float* W1, const float* W2, int ubase,
    const u16* xa, const u16* xb,
    const float* gadd17, const float* bias16,
    float* cstL, u16* hnext, int lane, int wid)
{
  const int r = lane & 15;
  const int grow = ((r >> 2) << 10) + ubase + (r & 3);
  const int m0 = wid*16;
  const int ao = (lane >> 4) << 3;
  f32x4 acc = {0.f,0.f,0.f,0.f};
  {
    const float* wp = W1 + (size_t)grow*1024 + ao;
    const u16* xp = xa + (size_t)(m0 + r)*1024 + ao;
    for (int kc = 0; kc < 32; ++kc){
      short8 bfr = ldw8(wp + kc*32);
      acc = MFMA(*(const short8*)(xp + kc*32), bfr, acc);
    }
  }
  if (W2){
    const float* wp = W2 + (size_t)grow*1024 + ao;
    const u16* xp = xb + (size_t)(m0 + r)*1024 + ao;
    for (int kc = 0; kc < 32; ++kc){
      short8 bfr = ldw8(wp + kc*32);
      acc = MFMA(*(const short8*)(xp + kc*32), bfr, acc);
    }
  }
  float v[4], vf[4], vg[4], vo[4];
#pragma unroll
  for (int q = 0; q < 4; ++q){
    const int brow = m0 + ((lane >> 4) << 2) + q;
    float x = acc[q];
    if (gadd17) x += gadd17[brow*17 + r];
    if (bias16) x += bias16[r];
    v[q] = x;
  }
#pragma unroll
  for (int q = 0; q < 4; ++q){
    vf[q] = __shfl_xor(v[q], 4, 64);
    vg[q] = __shfl_xor(v[q], 8, 64);
    vo[q] = __shfl_xor(v[q], 12, 64);
  }
  if (r < 4){
#pragma unroll
    for (int q = 0; q < 4; ++q){
      const int brow = m0 + ((lane >> 4) << 2) + q;
      float c = sigm(vf[q])*cstL[r*64 + brow] + sigm(v[q])*tanh_(vg[q]);
      const float h = sigm(vo[q])*tanh_(c);
      cstL[r*64 + brow] = c;
      hnext[(size_t)brow*1024 + ubase + r] = f2bf(h);
    }
  }
}

__global__ void init_kernel(const float* latent, char* ws){
  const int i = blockIdx.x*blockDim.x + threadIdx.x;
  u32* flags = (u32*)(ws + WS_FLAGS);
  u16* lat   = (u16*)(ws + WS_LAT);
  u16* noteb = (u16*)(ws + WS_NOTE);
  u16* hc0b  = (u16*)(ws + WS_HC0);
  u16* hc1b  = (u16*)(ws + WS_HC1);
  if (i < 256) flags[i] = 0u;
  if (i < 64*512) lat[i] = f2bf(latent[i]);
  if (i < 2*64*416) noteb[i] = 0;
  if (i < 64*1024){ hc0b[i] = 0; hc1b[i] = 0; }
}

__global__ void __launch_bounds__(256, 1) decoder_kernel(Params P){
  extern __shared__ char smem[];
  const int wg = blockIdx.x;
  const int tid = threadIdx.x;
  const int lane = tid & 63;
  const int wid = tid >> 6;

  u32* flags = (u32*)(P.ws + WS_FLAGS);
  const u16* lat = (const u16*)(P.ws + WS_LAT);
  u16* noteb = (u16*)(P.ws + WS_NOTE);
  u16* hd0b  = (u16*)(P.ws + WS_HD0);
  u16* hd1b  = (u16*)(P.ws + WS_HD1);
  u16* hc0b  = (u16*)(P.ws + WS_HC0);
  u16* hc1b  = (u16*)(P.ws + WS_HC1);
  u16* embA  = (u16*)(P.ws + WS_EMB);

  float* g_sc  = (float*)(smem + L_GSC);
  float* g_c0x = (float*)(smem + L_GC0X);
  float* cc0   = (float*)(smem + L_CC0);
  float* cc1   = (float*)(smem + L_CC1);
  float* bc1   = (float*)(smem + L_BC1);
  u16* Wd0   = (u16*)(smem + L_WD0);
  u16* Wemb  = (u16*)(smem + L_WEMB);
  float* g0e = (float*)(smem + L_G0E);
  float* cst0 = (float*)(smem + L_CST0);
  float* bd0  = (float*)(smem + L_BD0);
  u16* Wd1   = (u16*)(smem + L_WD1);
  float* cst1 = (float*)(smem + L_CST1);
  float* bd1  = (float*)(smem + L_BD1);
  u16* Wpj   = (u16*)(smem + L_WPJ);
  float* bpj  = (float*)(smem + L_BPJ);

  const bool is_d0 = (wg < 128);
  const bool is_pj = (wg >= 192 && wg < 248);

  /* ---------------- prologue: stage weights into LDS (fp32 -> bf16) ---------------- */
  if (is_d0){
    for (int r = wid; r < 32; r += 4){
      const int grow = ((r >> 3) << 10) + 8*wg + (r & 7);
      const float* wih = P.Wih_d0 + (size_t)grow*901;
      const float* whh = P.Whh_d0 + (size_t)grow*1024;
      u16* dst = Wd0 + (size_t)r*KD0;
      for (int c = lane; c < 416; c += 64) dst[c] = (c < 389) ? f2bf(wih[c]) : (u16)0;
      for (int c = lane; c < 1024; c += 64) dst[416 + c] = f2bf(whh[c]);
      u16* dste = Wemb + (size_t)r*KEMB;
      for (int c = lane; c < 512; c += 64) dste[c] = f2bf(wih[389 + c]);
    }
    if (tid < 32){
      const int grow = ((tid >> 3) << 10) + 8*wg + (tid & 7);
      bd0[tid] = P.bih_d0[grow] + P.bhh_d0[grow];
    }
  } else {
    const int wl = wg - 128;
    for (int r = wid; r < 32; r += 4){
      const int grow = ((r >> 3) << 10) + 8*wl + (r & 7);
      const float* wih = P.Wih_d1 + (size_t)grow*1024;
      const float* whh = P.Whh_d1 + (size_t)grow*1024;
      u16* dst = Wd1 + (size_t)r*KD1;
      for (int c = lane; c < 1024; c += 64) dst[c] = f2bf(wih[c]);
      for (int c = lane; c < 1024; c += 64) dst[1024 + c] = f2bf(whh[c]);
    }
    if (tid < 32){
      const int grow = ((tid >> 3) << 10) + 8*wl + (tid & 7);
      bd1[tid] = P.bih_d1[grow] + P.bhh_d1[grow];
    }
    if (is_pj){
      const int pi = wg - 192;
      for (int r = wid; r < 7; r += 4){
        const int row = pi*7 + r;
        u16* dst = Wpj + (size_t)r*KPROJ;
        if (row < 389){
          const float* w = P.Wdo + (size_t)row*1024;
          for (int c = lane; c < 1024; c += 64) dst[c] = f2bf(w[c]);
        } else {
          for (int c = lane; c < 1024; c += 64) dst[c] = 0;
        }
      }
      if (tid < 7){
        const int row = pi*7 + tid;
        bpj[tid] = (row < 389) ? P.bdo[row] : 0.f;
      }
    }
  }
  if (tid < 256){ cc0[tid] = 0.f; cc1[tid] = 0.f; }
  if (tid < 16){
    const int grow = ((tid >> 2) << 10) + 4*wg + (tid & 3);
    bc1[tid] = P.bih_c1[grow] + P.bhh_c1[grow];
  }
  /* g_c0x = latent @ Wih_c0^T + (bih_c0+bhh_c0), this CU's 16 gate-rows; [64][17] */
  {
    const int r = lane & 15;
    const int grow = ((r >> 2) << 10) + 4*wg + (r & 3);
    const float* wp = P.Wih_c0 + (size_t)grow*512 + ((lane >> 4) << 3);
    const int m0 = wid*16;
    const u16* xp = lat + (size_t)(m0 + r)*512 + ((lane >> 4) << 3);
    f32x4 acc = {0.f,0.f,0.f,0.f};
    for (int kc = 0; kc < 16; ++kc){
      short8 bfr = ldw8(wp + kc*32);
      acc = MFMA(*(const short8*)(xp + kc*32), bfr, acc);
    }
    const float bias = P.bih_c0[grow] + P.bhh_c0[grow];
#pragma unroll
    for (int q = 0; q < 4; ++q)
      g_c0x[(m0 + ((lane >> 4) << 2) + q)*17 + r] = acc[q] + bias;
  }
  __syncthreads();

  u32 ep = 0;

  /* ---------------- conductor: 16 sequential steps ---------------- */
  for (int s = 0; s < 16; ++s){
    const int pc = s & 1;
    const u16* hc0_p = hc0b + (size_t)pc*Bz*1024;
    u16*       hc0_n = hc0b + (size_t)(pc ^ 1)*Bz*1024;
    const u16* hc1_p = hc1b + (size_t)pc*Bz*1024;
    u16*       hc1_n = hc1b + (size_t)(pc ^ 1)*Bz*1024;

    cond_stage(P.Whh_c0, nullptr, 4*wg, hc0_p, nullptr, g_c0x, nullptr, cc0, hc0_n, lane, wid);
    gbar(flags, wg, ++ep);
    cond_stage(P.Wih_c1, P.Whh_c1, 4*wg, hc0_n, hc1_p, nullptr, bc1, cc1, hc1_n, lane, wid);
    gbar(flags, wg, ++ep);
    if (wg < 32){
      /* emb = tanh(hc1_new @ Wco^T + bco); this CU: rows 16*wg..+16 */
      const int r = lane & 15;
      const int row = 16*wg + r;
      const float* wp = P.Wco + (size_t)row*1024 + ((lane >> 4) << 3);
      const int m0 = wid*16;
      const u16* xp = hc1_n + (size_t)(m0 + r)*1024 + ((lane >> 4) << 3);
      f32x4 acc = {0.f,0.f,0.f,0.f};
      for (int kc = 0; kc < 32; ++kc){
        short8 bfr = ldw8(wp + kc*32);
        acc = MFMA(*(const short8*)(xp + kc*32), bfr, acc);
      }
      const float bias = P.bco[row];
#pragma unroll
      for (int q = 0; q < 4; ++q){
        const int brow = m0 + ((lane >> 4) << 2) + q;
        embA[((size_t)(s*64 + brow))*512 + row] = f2bf(tanh_(acc[q] + bias));
      }
    }
    gbar(flags, wg, ++ep);
  }

  /* ---------------- decoder: 16 subsequences x 32 steps ---------------- */
  for (int s = 0; s < 16; ++s){
    /* subsequence init: load h/c inits; precompute emb contribution to d0 gates */
    if (is_d0){
      for (int it = tid; it < 512; it += 256){
        const int b = it & 63, ul = it >> 6;
        const size_t src = ((size_t)(s*2 + 0)*64 + b)*1024 + 8*wg + ul;
        cst0[ul*64 + b] = P.c0_dec[src];
        hd0b[(size_t)b*1024 + 8*wg + ul] = f2bf(P.h0_dec[src]);
      }
      const int mh = wid & 1, nh = wid >> 1;
      const int ao = (lane >> 4) << 3;
      const u16* Wn = Wemb + (size_t)(nh*16 + (lane & 15))*KEMB + ao;
      const u16* ea = embA + (size_t)s*64*512;
      const u16* a0p = ea + (size_t)(mh*32 + (lane & 15))*512 + ao;
      const u16* a1p = a0p + (size_t)16*512;
      f32x4 acc0 = {0.f,0.f,0.f,0.f}, acc1 = {0.f,0.f,0.f,0.f};
#pragma unroll 4
      for (int kc = 0; kc < 16; ++kc){
        short8 bfr = *(const short8*)(Wn + kc*32);
        acc0 = MFMA(*(const short8*)(a0p + kc*32), bfr, acc0);
        acc1 = MFMA(*(const short8*)(a1p + kc*32), bfr, acc1);
      }
      const int col = nh*16 + (lane & 15);
      const int r0  = mh*32 + ((lane >> 4) << 2);
      const float bias = bd0[col];
#pragma unroll
      for (int q = 0; q < 4; ++q){
        g0e[(r0 + q)*33 + col]      = acc0[q] + bias;
        g0e[(r0 + 16 + q)*33 + col] = acc1[q] + bias;
      }
    } else {
      const int wl = wg - 128;
      for (int it = tid; it < 512; it += 256){
        const int b = it & 63, ul = it >> 6;
        const size_t src = ((size_t)(s*2 + 1)*64 + b)*1024 + 8*wl + ul;
        cst1[ul*64 + b] = P.c0_dec[src];
        hd1b[(size_t)b*1024 + 8*wl + ul] = f2bf(P.h0_dec[src]);
      }
    }
    gbar(flags, wg, ++ep);

    for (int t = 0; t < 32; ++t){
      const int p = t & 1;
      const u16* note_p = noteb + (size_t)p*Bz*416;
      u16*       note_n = noteb + (size_t)(p ^ 1)*Bz*416;
      const u16* hd0_p = hd0b + (size_t)p*Bz*1024;
      u16*       hd0_n = hd0b + (size_t)(p ^ 1)*Bz*1024;
      const u16* hd1_p = hd1b + (size_t)p*Bz*1024;
      u16*       hd1_n = hd1b + (size_t)(p ^ 1)*Bz*1024;

      /* stage d0 */
      if (is_d0){
        stage_cell32(Wd0, KD0, note_p, 416, 13, hd0_p, 1024, 32, 416, g_sc, lane, wid);
        __syncthreads();
        cell_pointwise(g_sc, g0e, nullptr, cst0, hd0_n, 8*wg, tid);
      }
      gbar(flags, wg, ++ep);

      /* stage d1 */
      if (!is_d0){
        stage_cell32(Wd1, KD1, hd0_n, 1024, 32, hd1_p, 1024, 32, 1024, g_sc, lane, wid);
        __syncthreads();
        cell_pointwise(g_sc, nullptr, bd1, cst1, hd1_n, 8*(wg - 128), tid);
      }
      gbar(flags, wg, ++ep);

      /* stage proj */
      if (is_pj){
        const int pi = wg - 192;
        const int r = lane & 15;
        const int rw = (r < 7) ? r : ((r < 14) ? r - 7 : r - 14);
        const int ao = (lane >> 4) << 3;
        const u16* wp = Wpj + (size_t)rw*KPROJ + ao;
        const int m0 = wid*16;
        const u16* xp = hd1_n + (size_t)(m0 + r)*1024 + ao;
        f32x4 acc = {0.f,0.f,0.f,0.f};
#pragma unroll 4
        for (int kc = 0; kc < 32; ++kc){
          short8 bfr = *(const short8*)(wp + kc*32);
          acc = MFMA(*(const short8*)(xp + kc*32), bfr, acc);
        }
        const int row = pi*7 + r;
        if (r < 7 && row < 389){
          const int seq = s*32 + t;
          const float bias = bpj[r];
#pragma unroll
          for (int q = 0; q < 4; ++q){
            const int brow = m0 + ((lane >> 4) << 2) + q;
            const float nv = tanh_(acc[q] + bias);
            P.out[((size_t)brow*512 + seq)*389 + row] = nv;
            note_n[(size_t)brow*416 + row] = f2bf(nv);
          }
        }
      }
      gbar(flags, wg, ++ep);
    }
  }
}

extern "C" void kernel_launch(void* const* d_in, const int* in_sizes, int n_in,
                              void* d_out, int out_size, void* d_ws, size_t ws_size,
                              hipStream_t stream){
  (void)in_sizes; (void)n_in; (void)out_size;
  if (ws_size < (size_t)WS_END) return;  /* not enough scratch: leave poison visible */

  Params P;
  P.latent = (const float*)d_in[0];
  P.h0_dec = (const float*)d_in[3];
  P.c0_dec = (const float*)d_in[4];
  P.Wih_c0 = (const float*)d_in[5];  P.Whh_c0 = (const float*)d_in[6];
  P.bih_c0 = (const float*)d_in[7];  P.bhh_c0 = (const float*)d_in[8];
  P.Wih_c1 = (const float*)d_in[9];  P.Whh_c1 = (const float*)d_in[10];
  P.bih_c1 = (const float*)d_in[11]; P.bhh_c1 = (const float*)d_in[12];
  P.Wco    = (const float*)d_in[13]; P.bco    = (const float*)d_in[14];
  P.Wih_d0 = (const float*)d_in[15]; P.Whh_d0 = (const float*)d_in[16];
  P.bih_d0 = (const float*)d_in[17]; P.bhh_d0 = (const float*)d_in[18];
  P.Wih_d1 = (const float*)d_in[19]; P.Whh_d1 = (const float*)d_in[20];
  P.bih_d1 = (const float*)d_in[21]; P.bhh_d1 = (const float*)d_in[22];
  P.Wdo    = (const float*)d_in[23]; P.bdo    = (const float*)d_in[24];
  P.out = (float*)d_out;
  P.ws  = (char*)d_ws;

  hipLaunchKernelGGL(init_kernel, dim3(256), dim3(256), 0, stream,
                     (const float*)d_in[0], (char*)d_ws);

  hipFuncSetAttribute(reinterpret_cast<const void*>(&decoder_kernel),
                      hipFuncAttributeMaxDynamicSharedMemorySize, LDS_BYTES);
  hipLaunchKernelGGL(decoder_kernel, dim3(NWG), dim3(256), LDS_BYTES, stream, P);
}

// Round 2
// 34301.273 us; speedup vs baseline: 2.4309x; 2.4309x over previous
//
#include <hip/hip_runtime.h>
#include <hip/hip_bf16.h>

typedef unsigned int  u32;
typedef unsigned short u16;
typedef unsigned long long u64;
typedef __attribute__((ext_vector_type(8))) short short8;
typedef __attribute__((ext_vector_type(4))) float f32x4;

#define MFMA(a,b,c) __builtin_amdgcn_mfma_f32_16x16x32_bf16(a,b,c,0,0,0)

#define NWG    256
#define Bz     64
#define KD0    1448   /* 416 + 1024 + 8 pad */
#define KD1    2056   /* 2048 + 8 pad */
#define KEMB   520    /* 512 + 8 pad */
#define KPROJ  1032   /* 1024 + 8 pad */

/* workspace layout (bytes) */
#define WS_FLAGS 0
#define WS_LAT   1024
#define WS_NOTE  (WS_LAT + 64*512*2)
#define WS_HD0   (WS_NOTE + 2*64*416*2)
#define WS_HD1   (WS_HD0 + 2*64*1024*2)
#define WS_HC0   (WS_HD1 + 2*64*1024*2)
#define WS_HC1   (WS_HC0 + 2*64*1024*2)
#define WS_EMB   (WS_HC1 + 2*64*1024*2)
#define WS_END   (WS_EMB + 16*64*512*2)

/* LDS layout (bytes) */
#define L_GSC   0                       /* 64*33 f32 = 8448 */
#define L_GC0X  8448                    /* 64*17 f32 = 4352 */
#define L_CC0   12800                   /* 4*64 f32 */
#define L_CC1   13824
#define L_BC1   14848                   /* 16 f32 */
#define L_ROLE  14912
/* d0 role */
#define L_WD0   L_ROLE                          /* 32*KD0*2 = 92672 */
#define L_WEMB  (L_ROLE + 32*KD0*2)             /* 32*KEMB*2 = 33280 */
#define L_G0E   (L_WEMB + 32*KEMB*2)            /* 64*33 f32 = 8448 */
#define L_CST0  (L_G0E + 8448)                  /* 8*64 f32 */
#define L_BD0   (L_CST0 + 2048)                 /* 32 f32 */
/* d1 role */
#define L_WD1   L_ROLE                          /* 32*KD1*2 = 131584 */
#define L_CST1  (L_ROLE + 32*KD1*2)
#define L_BD1   (L_CST1 + 2048)
#define L_WPJ   (L_BD1 + 128)                   /* 7*KPROJ*2 = 14448 */
#define L_BPJ   (L_WPJ + 7*KPROJ*2)             /* 7 f32 -> end 163148 < 163840 */

#define LDS_BYTES 163840

__device__ __forceinline__ u16 f2bf(float f){
  u32 u = __float_as_uint(f);
  u32 r = (u + 0x7FFFu + ((u >> 16) & 1u)) >> 16;
  return (u16)r;
}
__device__ __forceinline__ float sigm(float x){ return 1.f/(1.f + __expf(-x)); }
__device__ __forceinline__ float tanh_(float x){
  float e = __expf(-2.f*fabsf(x));
  float t = (1.f - e)/(1.f + e);
  return x < 0.f ? -t : t;
}
__device__ __forceinline__ short8 ldw8(const float* p0){
  short8 r;
#pragma unroll
  for (int j = 0; j < 8; ++j) r[j] = (short)f2bf(p0[j]);
  return r;
}

/* ---- fine-grain cross-CU stores: write-through to IF (sc1), no L2 writeback ---- */
__device__ __forceinline__ void st32(u32* p, u32 v){
  __hip_atomic_store(p, v, __ATOMIC_RELAXED, __HIP_MEMORY_SCOPE_AGENT);
}
__device__ __forceinline__ void st16(u16* p, u16 v){
  asm volatile("global_store_short %0, %1, off sc1" :: "v"(p), "v"((u32)v) : "memory");
}

/* contention-free grid barrier: per-WG flag + min-scan by wave 0.
   Release side: sc1 data stores already drained by vmcnt(0) (syncthreads) ->
   relaxed flag store only. Acquire side: buffer_inv (cheap) so plain cached
   loads see IF-fresh data. NO buffer_wbl2 anywhere. */
__device__ __forceinline__ void gbar(u32* flags, int wg, u32 ep){
  asm volatile("s_waitcnt vmcnt(0)" ::: "memory");
  __syncthreads();
  if (threadIdx.x < 64){
    const int lane = threadIdx.x;
    if (lane == 0)
      __hip_atomic_store(&flags[wg], ep, __ATOMIC_RELAXED, __HIP_MEMORY_SCOPE_AGENT);
    for (;;){
      u32 m = 0xFFFFFFFFu;
#pragma unroll
      for (int j = 0; j < 4; ++j){
        u32 v = __hip_atomic_load(&flags[lane*4 + j], __ATOMIC_RELAXED, __HIP_MEMORY_SCOPE_AGENT);
        m = v < m ? v : m;
      }
#pragma unroll
      for (int off = 32; off; off >>= 1){
        u32 o = (u32)__shfl_xor((int)m, off, 64);
        m = o < m ? o : m;
      }
      if (m >= ep) break;
      __builtin_amdgcn_s_sleep(1);
    }
    __builtin_amdgcn_fence(__ATOMIC_ACQUIRE, "agent");  /* buffer_inv sc1 */
  }
  __syncthreads();
}

struct Params {
  const float *latent, *h0_dec, *c0_dec;
  const float *Wih_c0, *Whh_c0, *bih_c0, *bhh_c0;
  const float *Wih_c1, *Whh_c1, *bih_c1, *bhh_c1;
  const float *Wco, *bco;
  const float *Wih_d0, *Whh_d0, *bih_d0, *bhh_d0;
  const float *Wih_d1, *Whh_d1, *bih_d1, *bhh_d1;
  const float *Wdo, *bdo;
  float* out;
  char* ws;
};

/* [64 x 32cols] = x @ W^T, W in LDS row-major [32][ldw], x bf16 in global.
   waves: M2N2 (mh=wid&1 -> batch half, nh=wid>>1 -> 16-col half). */
__device__ __forceinline__ void stage_cell32(
    const u16* W, int ldw,
    const u16* xa, int lda, int na,
    const u16* xb, int ldb, int nb, int kwb,
    float* g_sc, int lane, int wid)
{
  const int mh = wid & 1, nh = wid >> 1;
  const int ao = (lane >> 4) << 3;
  const u16* Wn = W + (size_t)(nh*16 + (lane & 15))*ldw + ao;
  f32x4 acc0 = {0.f,0.f,0.f,0.f}, acc1 = {0.f,0.f,0.f,0.f};
  const u16* xa0 = xa + (size_t)(mh*32 + (lane & 15))*lda + ao;
  const u16* xa1 = xa0 + (size_t)16*lda;
#pragma unroll 4
  for (int kc = 0; kc < na; ++kc){
    short8 bfr = *(const short8*)(Wn + kc*32);
    acc0 = MFMA(*(const short8*)(xa0 + kc*32), bfr, acc0);
    acc1 = MFMA(*(const short8*)(xa1 + kc*32), bfr, acc1);
  }
  const u16* Wn2 = Wn + kwb;
  const u16* xb0 = xb + (size_t)(mh*32 + (lane & 15))*ldb + ao;
  const u16* xb1 = xb0 + (size_t)16*ldb;
#pragma unroll 4
  for (int kc = 0; kc < nb; ++kc){
    short8 bfr = *(const short8*)(Wn2 + kc*32);
    acc0 = MFMA(*(const short8*)(xb0 + kc*32), bfr, acc0);
    acc1 = MFMA(*(const short8*)(xb1 + kc*32), bfr, acc1);
  }
  const int col = nh*16 + (lane & 15);
  const int r0  = mh*32 + ((lane >> 4) << 2);
#pragma unroll
  for (int q = 0; q < 4; ++q){
    g_sc[(r0 + q)*33 + col]      = acc0[q];
    g_sc[(r0 + 16 + q)*33 + col] = acc1[q];
  }
}

/* LSTM pointwise; thread -> (b = tid&63, unit pair k = tid>>6), packed u32 h store */
__device__ __forceinline__ void cell_pointwise(
    const float* g_sc, const float* gadd, const float* bias,
    float* cst, u16* hnext, int u0, int tid)
{
  const int b = tid & 63;
  const int k = tid >> 6;
  u32 hp = 0;
#pragma unroll
  for (int j = 0; j < 2; ++j){
    const int u = 2*k + j;
    float gi = g_sc[b*33 + u];
    float gf = g_sc[b*33 + 8 + u];
    float gg = g_sc[b*33 + 16 + u];
    float go = g_sc[b*33 + 24 + u];
    if (gadd){
      gi += gadd[b*33 + u];      gf += gadd[b*33 + 8 + u];
      gg += gadd[b*33 + 16 + u]; go += gadd[b*33 + 24 + u];
    }
    if (bias){
      gi += bias[u]; gf += bias[8 + u]; gg += bias[16 + u]; go += bias[24 + u];
    }
    float c = sigm(gf)*cst[u*64 + b] + sigm(gi)*tanh_(gg);
    const float h = sigm(go)*tanh_(c);
    cst[u*64 + b] = c;
    hp |= ((u32)f2bf(h)) << (16*j);
  }
  st32((u32*)&hnext[(size_t)b*1024 + u0 + 2*k], hp);
}

/* conductor LSTM stage, M4N1, weights streamed from global fp32. */
__device__ __forceinline__ void cond_stage(
    const float* W1, const float* W2, int ubase,
    const u16* xa, const u16* xb,
    const float* gadd17, const float* bias16,
    float* cstL, u16* hnext, int lane, int wid)
{
  const int r = lane & 15;
  const int grow = ((r >> 2) << 10) + ubase + (r & 3);
  const int m0 = wid*16;
  const int ao = (lane >> 4) << 3;
  f32x4 acc = {0.f,0.f,0.f,0.f};
  {
    const float* wp = W1 + (size_t)grow*1024 + ao;
    const u16* xp = xa + (size_t)(m0 + r)*1024 + ao;
    for (int kc = 0; kc < 32; ++kc){
      short8 bfr = ldw8(wp + kc*32);
      acc = MFMA(*(const short8*)(xp + kc*32), bfr, acc);
    }
  }
  if (W2){
    const float* wp = W2 + (size_t)grow*1024 + ao;
    const u16* xp = xb + (size_t)(m0 + r)*1024 + ao;
    for (int kc = 0; kc < 32; ++kc){
      short8 bfr = ldw8(wp + kc*32);
      acc = MFMA(*(const short8*)(xp + kc*32), bfr, acc);
    }
  }
  float v[4], vf[4], vg[4], vo[4];
#pragma unroll
  for (int q = 0; q < 4; ++q){
    const int brow = m0 + ((lane >> 4) << 2) + q;
    float x = acc[q];
    if (gadd17) x += gadd17[brow*17 + r];
    if (bias16) x += bias16[r];
    v[q] = x;
  }
#pragma unroll
  for (int q = 0; q < 4; ++q){
    vf[q] = __shfl_xor(v[q], 4, 64);
    vg[q] = __shfl_xor(v[q], 8, 64);
    vo[q] = __shfl_xor(v[q], 12, 64);
  }
  if (r < 4){
#pragma unroll
    for (int q = 0; q < 4; ++q){
      const int brow = m0 + ((lane >> 4) << 2) + q;
      float c = sigm(vf[q])*cstL[r*64 + brow] + sigm(v[q])*tanh_(vg[q]);
      const float h = sigm(vo[q])*tanh_(c);
      cstL[r*64 + brow] = c;
      st16(&hnext[(size_t)brow*1024 + ubase + r], f2bf(h));
    }
  }
}

__global__ void init_kernel(const float* latent, char* ws){
  const int i = blockIdx.x*blockDim.x + threadIdx.x;
  u32* flags = (u32*)(ws + WS_FLAGS);
  u16* lat   = (u16*)(ws + WS_LAT);
  u16* noteb = (u16*)(ws + WS_NOTE);
  u16* hc0b  = (u16*)(ws + WS_HC0);
  u16* hc1b  = (u16*)(ws + WS_HC1);
  if (i < 256) flags[i] = 0u;
  if (i < 64*512) lat[i] = f2bf(latent[i]);
  if (i < 2*64*416) noteb[i] = 0;
  if (i < 64*1024){ hc0b[i] = 0; hc1b[i] = 0; }
}

__global__ void __launch_bounds__(256, 1) decoder_kernel(Params P){
  extern __shared__ char smem[];
  const int wg = blockIdx.x;
  const int tid = threadIdx.x;
  const int lane = tid & 63;
  const int wid = tid >> 6;

  u32* flags = (u32*)(P.ws + WS_FLAGS);
  const u16* lat = (const u16*)(P.ws + WS_LAT);
  u16* noteb = (u16*)(P.ws + WS_NOTE);
  u16* hd0b  = (u16*)(P.ws + WS_HD0);
  u16* hd1b  = (u16*)(P.ws + WS_HD1);
  u16* hc0b  = (u16*)(P.ws + WS_HC0);
  u16* hc1b  = (u16*)(P.ws + WS_HC1);
  u16* embA  = (u16*)(P.ws + WS_EMB);

  float* g_sc  = (float*)(smem + L_GSC);
  float* g_c0x = (float*)(smem + L_GC0X);
  float* cc0   = (float*)(smem + L_CC0);
  float* cc1   = (float*)(smem + L_CC1);
  float* bc1   = (float*)(smem + L_BC1);
  u16* Wd0   = (u16*)(smem + L_WD0);
  u16* Wemb  = (u16*)(smem + L_WEMB);
  float* g0e = (float*)(smem + L_G0E);
  float* cst0 = (float*)(smem + L_CST0);
  float* bd0  = (float*)(smem + L_BD0);
  u16* Wd1   = (u16*)(smem + L_WD1);
  float* cst1 = (float*)(smem + L_CST1);
  float* bd1  = (float*)(smem + L_BD1);
  u16* Wpj   = (u16*)(smem + L_WPJ);
  float* bpj  = (float*)(smem + L_BPJ);

  const bool is_d0 = (wg < 128);
  const bool is_pj = (wg >= 192 && wg < 248);

  /* ---------------- prologue: stage weights into LDS (fp32 -> bf16) ---------------- */
  if (is_d0){
    for (int r = wid; r < 32; r += 4){
      const int grow = ((r >> 3) << 10) + 8*wg + (r & 7);
      const float* wih = P.Wih_d0 + (size_t)grow*901;
      const float* whh = P.Whh_d0 + (size_t)grow*1024;
      u16* dst = Wd0 + (size_t)r*KD0;
      for (int c = lane; c < 416; c += 64) dst[c] = (c < 389) ? f2bf(wih[c]) : (u16)0;
      for (int c = lane; c < 1024; c += 64) dst[416 + c] = f2bf(whh[c]);
      u16* dste = Wemb + (size_t)r*KEMB;
      for (int c = lane; c < 512; c += 64) dste[c] = f2bf(wih[389 + c]);
    }
    if (tid < 32){
      const int grow = ((tid >> 3) << 10) + 8*wg + (tid & 7);
      bd0[tid] = P.bih_d0[grow] + P.bhh_d0[grow];
    }
  } else {
    const int wl = wg - 128;
    for (int r = wid; r < 32; r += 4){
      const int grow = ((r >> 3) << 10) + 8*wl + (r & 7);
      const float* wih = P.Wih_d1 + (size_t)grow*1024;
      const float* whh = P.Whh_d1 + (size_t)grow*1024;
      u16* dst = Wd1 + (size_t)r*KD1;
      for (int c = lane; c < 1024; c += 64) dst[c] = f2bf(wih[c]);
      for (int c = lane; c < 1024; c += 64) dst[1024 + c] = f2bf(whh[c]);
    }
    if (tid < 32){
      const int grow = ((tid >> 3) << 10) + 8*wl + (tid & 7);
      bd1[tid] = P.bih_d1[grow] + P.bhh_d1[grow];
    }
    if (is_pj){
      const int pi = wg - 192;
      for (int r = wid; r < 7; r += 4){
        const int row = pi*7 + r;
        u16* dst = Wpj + (size_t)r*KPROJ;
        if (row < 389){
          const float* w = P.Wdo + (size_t)row*1024;
          for (int c = lane; c < 1024; c += 64) dst[c] = f2bf(w[c]);
        } else {
          for (int c = lane; c < 1024; c += 64) dst[c] = 0;
        }
      }
      if (tid < 7){
        const int row = pi*7 + tid;
        bpj[tid] = (row < 389) ? P.bdo[row] : 0.f;
      }
    }
  }
  if (tid < 256){ cc0[tid] = 0.f; cc1[tid] = 0.f; }
  if (tid < 16){
    const int grow = ((tid >> 2) << 10) + 4*wg + (tid & 3);
    bc1[tid] = P.bih_c1[grow] + P.bhh_c1[grow];
  }
  /* g_c0x = latent @ Wih_c0^T + (bih_c0+bhh_c0), this CU's 16 gate-rows; [64][17] */
  {
    const int r = lane & 15;
    const int grow = ((r >> 2) << 10) + 4*wg + (r & 3);
    const float* wp = P.Wih_c0 + (size_t)grow*512 + ((lane >> 4) << 3);
    const int m0 = wid*16;
    const u16* xp = lat + (size_t)(m0 + r)*512 + ((lane >> 4) << 3);
    f32x4 acc = {0.f,0.f,0.f,0.f};
    for (int kc = 0; kc < 16; ++kc){
      short8 bfr = ldw8(wp + kc*32);
      acc = MFMA(*(const short8*)(xp + kc*32), bfr, acc);
    }
    const float bias = P.bih_c0[grow] + P.bhh_c0[grow];
#pragma unroll
    for (int q = 0; q < 4; ++q)
      g_c0x[(m0 + ((lane >> 4) << 2) + q)*17 + r] = acc[q] + bias;
  }
  __syncthreads();

  u32 ep = 0;

  /* ---------------- conductor: 16 sequential steps ---------------- */
  for (int s = 0; s < 16; ++s){
    const int pc = s & 1;
    const u16* hc0_p = hc0b + (size_t)pc*Bz*1024;
    u16*       hc0_n = hc0b + (size_t)(pc ^ 1)*Bz*1024;
    const u16* hc1_p = hc1b + (size_t)pc*Bz*1024;
    u16*       hc1_n = hc1b + (size_t)(pc ^ 1)*Bz*1024;

    cond_stage(P.Whh_c0, nullptr, 4*wg, hc0_p, nullptr, g_c0x, nullptr, cc0, hc0_n, lane, wid);
    gbar(flags, wg, ++ep);
    cond_stage(P.Wih_c1, P.Whh_c1, 4*wg, hc0_n, hc1_p, nullptr, bc1, cc1, hc1_n, lane, wid);
    gbar(flags, wg, ++ep);
    if (wg < 32){
      /* emb = tanh(hc1_new @ Wco^T + bco); this CU: rows 16*wg..+16 */
      const int r = lane & 15;
      const int row = 16*wg + r;
      const float* wp = P.Wco + (size_t)row*1024 + ((lane >> 4) << 3);
      const int m0 = wid*16;
      const u16* xp = hc1_n + (size_t)(m0 + r)*1024 + ((lane >> 4) << 3);
      f32x4 acc = {0.f,0.f,0.f,0.f};
      for (int kc = 0; kc < 32; ++kc){
        short8 bfr = ldw8(wp + kc*32);
        acc = MFMA(*(const short8*)(xp + kc*32), bfr, acc);
      }
      const float bias = P.bco[row];
#pragma unroll
      for (int q = 0; q < 4; ++q){
        const int brow = m0 + ((lane >> 4) << 2) + q;
        st16(&embA[((size_t)(s*64 + brow))*512 + row], f2bf(tanh_(acc[q] + bias)));
      }
    }
    gbar(flags, wg, ++ep);
  }

  /* ---------------- decoder: 16 subsequences x 32 steps ---------------- */
  for (int s = 0; s < 16; ++s){
    /* subsequence init: load h/c inits; precompute emb contribution to d0 gates */
    if (is_d0){
      {
        const int b = tid & 63, k = tid >> 6;   /* unit pair 2k,2k+1 */
        const size_t src = ((size_t)(s*2 + 0)*64 + b)*1024 + 8*wg + 2*k;
        cst0[(2*k)*64 + b]     = P.c0_dec[src];
        cst0[(2*k + 1)*64 + b] = P.c0_dec[src + 1];
        u32 hp = (u32)f2bf(P.h0_dec[src]) | ((u32)f2bf(P.h0_dec[src + 1]) << 16);
        st32((u32*)&hd0b[(size_t)b*1024 + 8*wg + 2*k], hp);
      }
      const int mh = wid & 1, nh = wid >> 1;
      const int ao = (lane >> 4) << 3;
      const u16* Wn = Wemb + (size_t)(nh*16 + (lane & 15))*KEMB + ao;
      const u16* ea = embA + (size_t)s*64*512;
      const u16* a0p = ea + (size_t)(mh*32 + (lane & 15))*512 + ao;
      const u16* a1p = a0p + (size_t)16*512;
      f32x4 acc0 = {0.f,0.f,0.f,0.f}, acc1 = {0.f,0.f,0.f,0.f};
#pragma unroll 4
      for (int kc = 0; kc < 16; ++kc){
        short8 bfr = *(const short8*)(Wn + kc*32);
        acc0 = MFMA(*(const short8*)(a0p + kc*32), bfr, acc0);
        acc1 = MFMA(*(const short8*)(a1p + kc*32), bfr, acc1);
      }
      const int col = nh*16 + (lane & 15);
      const int r0  = mh*32 + ((lane >> 4) << 2);
      const float bias = bd0[col];
#pragma unroll
      for (int q = 0; q < 4; ++q){
        g0e[(r0 + q)*33 + col]      = acc0[q] + bias;
        g0e[(r0 + 16 + q)*33 + col] = acc1[q] + bias;
      }
    } else {
      const int wl = wg - 128;
      const int b = tid & 63, k = tid >> 6;
      const size_t src = ((size_t)(s*2 + 1)*64 + b)*1024 + 8*wl + 2*k;
      cst1[(2*k)*64 + b]     = P.c0_dec[src];
      cst1[(2*k + 1)*64 + b] = P.c0_dec[src + 1];
      u32 hp = (u32)f2bf(P.h0_dec[src]) | ((u32)f2bf(P.h0_dec[src + 1]) << 16);
      st32((u32*)&hd1b[(size_t)b*1024 + 8*wl + 2*k], hp);
    }
    gbar(flags, wg, ++ep);

    for (int t = 0; t < 32; ++t){
      const int p = t & 1;
      const u16* note_p = noteb + (size_t)p*Bz*416;
      u16*       note_n = noteb + (size_t)(p ^ 1)*Bz*416;
      const u16* hd0_p = hd0b + (size_t)p*Bz*1024;
      u16*       hd0_n = hd0b + (size_t)(p ^ 1)*Bz*1024;
      const u16* hd1_p = hd1b + (size_t)p*Bz*1024;
      u16*       hd1_n = hd1b + (size_t)(p ^ 1)*Bz*1024;

      /* stage d0 */
      if (is_d0){
        stage_cell32(Wd0, KD0, note_p, 416, 13, hd0_p, 1024, 32, 416, g_sc, lane, wid);
        __syncthreads();
        cell_pointwise(g_sc, g0e, nullptr, cst0, hd0_n, 8*wg, tid);
      }
      gbar(flags, wg, ++ep);

      /* stage d1 */
      if (!is_d0){
        stage_cell32(Wd1, KD1, hd0_n, 1024, 32, hd1_p, 1024, 32, 1024, g_sc, lane, wid);
        __syncthreads();
        cell_pointwise(g_sc, nullptr, bd1, cst1, hd1_n, 8*(wg - 128), tid);
      }
      gbar(flags, wg, ++ep);

      /* stage proj */
      if (is_pj){
        const int pi = wg - 192;
        const int r = lane & 15;
        const int rw = (r < 7) ? r : ((r < 14) ? r - 7 : r - 14);
        const int ao = (lane >> 4) << 3;
        const u16* wp = Wpj + (size_t)rw*KPROJ + ao;
        const int m0 = wid*16;
        const u16* xp = hd1_n + (size_t)(m0 + r)*1024 + ao;
        f32x4 acc = {0.f,0.f,0.f,0.f};
#pragma unroll 4
        for (int kc = 0; kc < 32; ++kc){
          short8 bfr = *(const short8*)(wp + kc*32);
          acc = MFMA(*(const short8*)(xp + kc*32), bfr, acc);
        }
        const int row = pi*7 + r;
        if (r < 7 && row < 389){
          const int seq = s*32 + t;
          const float bias = bpj[r];
#pragma unroll
          for (int q = 0; q < 4; ++q){
            const int brow = m0 + ((lane >> 4) << 2) + q;
            const float nv = tanh_(acc[q] + bias);
            P.out[((size_t)brow*512 + seq)*389 + row] = nv;
            st16(&note_n[(size_t)brow*416 + row], f2bf(nv));
          }
        }
      }
      gbar(flags, wg, ++ep);
    }
  }
}

extern "C" void kernel_launch(void* const* d_in, const int* in_sizes, int n_in,
                              void* d_out, int out_size, void* d_ws, size_t ws_size,
                              hipStream_t stream){
  (void)in_sizes; (void)n_in; (void)out_size;
  if (ws_size < (size_t)WS_END) return;  /* not enough scratch: leave poison visible */

  Params P;
  P.latent = (const float*)d_in[0];
  P.h0_dec = (const float*)d_in[3];
  P.c0_dec = (const float*)d_in[4];
  P.Wih_c0 = (const float*)d_in[5];  P.Whh_c0 = (const float*)d_in[6];
  P.bih_c0 = (const float*)d_in[7];  P.bhh_c0 = (const float*)d_in[8];
  P.Wih_c1 = (const float*)d_in[9];  P.Whh_c1 = (const float*)d_in[10];
  P.bih_c1 = (const float*)d_in[11]; P.bhh_c1 = (const float*)d_in[12];
  P.Wco    = (const float*)d_in[13]; P.bco    = (const float*)d_in[14];
  P.Wih_d0 = (const float*)d_in[15]; P.Whh_d0 = (const float*)d_in[16];
  P.bih_d0 = (const float*)d_in[17]; P.bhh_d0 = (const float*)d_in[18];
  P.Wih_d1 = (const float*)d_in[19]; P.Whh_d1 = (const float*)d_in[20];
  P.bih_d1 = (const float*)d_in[21]; P.bhh_d1 = (const float*)d_in[22];
  P.Wdo    = (const float*)d_in[23]; P.bdo    = (const float*)d_in[24];
  P.out = (float*)d_out;
  P.ws  = (char*)d_ws;

  hipLaunchKernelGGL(init_kernel, dim3(256), dim3(256), 0, stream,
                     (const float*)d_in[0], (char*)d_ws);

  hipFuncSetAttribute(reinterpret_cast<const void*>(&decoder_kernel),
                      hipFuncAttributeMaxDynamicSharedMemorySize, LDS_BYTES);
  hipLaunchKernelGGL(decoder_kernel, dim3(NWG), dim3(256), LDS_BYTES, stream, P);
}

// Round 3
// 32925.656 us; speedup vs baseline: 2.5325x; 1.0418x over previous
//
#include <hip/hip_runtime.h>
#include <hip/hip_bf16.h>

typedef unsigned int  u32;
typedef unsigned short u16;
typedef __attribute__((ext_vector_type(8))) short short8;
typedef __attribute__((ext_vector_type(4))) float f32x4;
typedef __attribute__((ext_vector_type(4))) unsigned int u32x4;
typedef __attribute__((ext_vector_type(2))) unsigned int u32x2;

#define MFMA(a,b,c) __builtin_amdgcn_mfma_f32_16x16x32_bf16(a,b,c,0,0,0)

#define NWG    256
#define KD0    1448   /* 416 + 1024 + 8 pad */
#define KD1    2056   /* 2048 + 8 pad */
#define KPROJ  1032   /* 1024 + 8 pad */

/* ---- workspace layout (bytes). granule layout: [K/8 granules][64 b][8 units] u16 ---- */
#define WS_FLAGS 0
#define WS_NOTE  4096                          /* 2 par x 52*64*8 u16 = 106496 B */
#define WS_HD0   (WS_NOTE + 2*52*64*8*2)       /* 2 par x 128*64*8 u16 = 262144 B */
#define WS_HD1   (WS_HD0 + 2*128*64*8*2)
#define WS_HC0   (WS_HD1 + 2*128*64*8*2)
#define WS_HC1   (WS_HC0 + 2*128*64*8*2)
#define WS_EMB   (WS_HC1 + 2*128*64*8*2)       /* 16 x 64gran*64*8 u16 = 1 MB */
#define WS_LAT   (WS_EMB + 15*64*64*8*2)       /* overlay on embA[15]: dead after prologue */
#define WS_END   (WS_EMB + 16*64*64*8*2)

#define NOTE_PAR 26624   /* u16 per parity */
#define HD_PAR   65536
#define HC_PAR   65536
#define EMB_S    32768

/* ---- LDS layout (bytes) ---- */
#define L_GSC   0                 /* 64*33 f32 = 8448 */
#define L_GC0X  8448              /* 64*17 f32 = 4352 */
#define L_CC0   12800             /* 4*64 f32 */
#define L_CC1   13824
#define L_BC1   14848             /* 16 f32 */
#define L_PACK  14912             /* 2048 B shared pack buffer */
#define L_ROLE  16960
/* d0 role */
#define L_WD0   L_ROLE                       /* 32*KD0*2 = 92672 */
#define L_G0E   (L_ROLE + 32*KD0*2)          /* 64*33 f32 = 8448 */
#define L_CST0  (L_G0E + 8448)               /* 8*64 f32 */
#define L_BD0   (L_CST0 + 2048)              /* 32 f32 */
#define L_WPJ   (L_BD0 + 128)                /* 16*KPROJ*2 = 33024 */
#define L_BPJ   (L_WPJ + 16*KPROJ*2)         /* 16 f32 -> end 153344 */
/* d1 role */
#define L_WD1   L_ROLE                       /* 32*KD1*2 = 131584 */
#define L_CST1  (L_ROLE + 32*KD1*2)
#define L_BD1   (L_CST1 + 2048)              /* end 150720 */
#define LDS_BYTES 153600

__device__ __forceinline__ u16 f2bf(float f){
  u32 u = __float_as_uint(f);
  u32 r = (u + 0x7FFFu + ((u >> 16) & 1u)) >> 16;
  return (u16)r;
}
__device__ __forceinline__ float sigm(float x){ return 1.f/(1.f + __expf(-x)); }
__device__ __forceinline__ float tanh_(float x){
  float e = __expf(-2.f*fabsf(x));
  float t = (1.f - e)/(1.f + e);
  return x < 0.f ? -t : t;
}
__device__ __forceinline__ short8 ldw8(const float* p0){
  short8 r;
#pragma unroll
  for (int j = 0; j < 8; ++j) r[j] = (short)f2bf(p0[j]);
  return r;
}

/* ---- sc1 (write-through to IF / L2-bypass) memory ops ---- */
__device__ __forceinline__ void gst1(u32* p, u32 v){
  asm volatile("global_store_dword %0, %1, off sc1" :: "v"(p), "v"(v) : "memory");
}
__device__ __forceinline__ void gst2(u16* p, u32x2 v){
  asm volatile("global_store_dwordx2 %0, %1, off sc1" :: "v"(p), "v"(v) : "memory");
}
__device__ __forceinline__ void gst4(u16* p, u32x4 v){
  asm volatile("global_store_dwordx4 %0, %1, off sc1" :: "v"(p), "v"(v) : "memory");
}
__device__ __forceinline__ u32x4 ld4_sc1(const u32* p){
  u32x4 v;
  asm volatile("global_load_dwordx4 %0, %1, off sc1\n\ts_waitcnt vmcnt(0)"
               : "=v"(v) : "v"(p) : "memory");
  return v;
}

/* grid barrier: coalesced dwordx4 flag scan (1 load-instr per lane per round) */
__device__ __forceinline__ void gbar(u32* flags, int wg, u32 ep){
  asm volatile("s_waitcnt vmcnt(0)" ::: "memory");
  __syncthreads();
  if (threadIdx.x < 64){
    const int lane = threadIdx.x;
    if (lane == 0) gst1(&flags[wg], ep);
    for (;;){
      u32x4 f = ld4_sc1(&flags[lane*4]);
      u32 a = f[0] < f[1] ? f[0] : f[1];
      u32 b = f[2] < f[3] ? f[2] : f[3];
      u32 m = a < b ? a : b;
#pragma unroll
      for (int off = 32; off; off >>= 1){
        u32 o = (u32)__shfl_xor((int)m, off, 64);
        m = o < m ? o : m;
      }
      if (m >= ep) break;
      __builtin_amdgcn_s_sleep(1);
    }
    __builtin_amdgcn_fence(__ATOMIC_ACQUIRE, "agent");  /* inv L2/L1 */
  }
  __syncthreads();
}

struct Params {
  const float *latent, *h0_dec, *c0_dec;
  const float *Wih_c0, *Whh_c0, *bih_c0, *bhh_c0;
  const float *Wih_c1, *Whh_c1, *bih_c1, *bhh_c1;
  const float *Wco, *bco;
  const float *Wih_d0, *Whh_d0, *bih_d0, *bhh_d0;
  const float *Wih_d1, *Whh_d1, *bih_d1, *bhh_d1;
  const float *Wdo, *bdo;
  float* out;
  char* ws;
};

/* 64x32 gates = x @ W^T. W: LDS rows [32][ldw] bf16. x: granule-packed global.
   A addr for element (row,k): ((k/8)*64 + row)*8 + k%8. M2N2 wave split. */
__device__ __forceinline__ void stage_gr(
    const u16* W, int ldw, const u16* xa, int na,
    const u16* xb, int nb, int kwb, float* g_sc, int lane, int wid)
{
  const int mh = wid & 1, nh = wid >> 1;
  const int q = lane >> 4, rr = lane & 15;
  const u16* Wn  = W + (size_t)(nh*16 + rr)*ldw + q*8;
  const u16* Wn2 = Wn + kwb;
  const u16* a0 = xa + ((size_t)q*64 + mh*32 + rr)*8;
  const u16* a1 = a0 + 128;
  const u16* b0 = xb + ((size_t)q*64 + mh*32 + rr)*8;
  const u16* b1 = b0 + 128;
  f32x4 acc0 = {0.f,0.f,0.f,0.f}, acc1 = {0.f,0.f,0.f,0.f};
#pragma unroll 4
  for (int kc = 0; kc < na; ++kc){
    short8 w = *(const short8*)(Wn + kc*32);
    acc0 = MFMA(*(const short8*)(a0 + (size_t)kc*2048), w, acc0);
    acc1 = MFMA(*(const short8*)(a1 + (size_t)kc*2048), w, acc1);
  }
#pragma unroll 4
  for (int kc = 0; kc < nb; ++kc){
    short8 w = *(const short8*)(Wn2 + kc*32);
    acc0 = MFMA(*(const short8*)(b0 + (size_t)kc*2048), w, acc0);
    acc1 = MFMA(*(const short8*)(b1 + (size_t)kc*2048), w, acc1);
  }
  const int col = nh*16 + rr, r0 = mh*32 + q*4;
#pragma unroll
  for (int i = 0; i < 4; ++i){
    g_sc[(r0 + i)*33 + col]      = acc0[i];
    g_sc[(r0 + 16 + i)*33 + col] = acc1[i];
  }
}

/* LSTM pointwise -> packed bf16 pair into LDS pack[64][4] u32 */
__device__ __forceinline__ void cell_pw(
    const float* g_sc, const float* gadd, const float* bias,
    float* cst, u32* pack, int tid)
{
  const int b = tid & 63, k = tid >> 6;
  u32 hp = 0;
#pragma unroll
  for (int j = 0; j < 2; ++j){
    const int u = 2*k + j;
    float gi = g_sc[b*33 + u];
    float gf = g_sc[b*33 + 8 + u];
    float gg = g_sc[b*33 + 16 + u];
    float go = g_sc[b*33 + 24 + u];
    if (gadd){
      gi += gadd[b*33 + u];      gf += gadd[b*33 + 8 + u];
      gg += gadd[b*33 + 16 + u]; go += gadd[b*33 + 24 + u];
    }
    if (bias){
      gi += bias[u]; gf += bias[8 + u]; gg += bias[16 + u]; go += bias[24 + u];
    }
    float c = sigm(gf)*cst[u*64 + b] + sigm(gi)*tanh_(gg);
    const float h = sigm(go)*tanh_(c);
    cst[u*64 + b] = c;
    hp |= ((u32)f2bf(h)) << (16*j);
  }
  pack[b*4 + k] = hp;
}

/* conductor stage: 4 units/WG, weights streamed fp32 from HBM, x granule-packed.
   Result bf16 into pack16[64][4]. */
__device__ __forceinline__ void cond_gr(
    const float* W1, const float* W2,
    const u16* xa, const u16* xb,
    const float* gadd17, const float* bias16,
    float* cstL, u16* pack16, int ubase, int lane, int wid)
{
  const int r = lane & 15, q = lane >> 4;
  const int grow = ((r >> 2) << 10) + ubase + (r & 3);
  const int m0 = wid*16;
  f32x4 acc = {0.f,0.f,0.f,0.f};
  {
    const float* wp = W1 + (size_t)grow*1024 + q*8;
    const u16* xp = xa + ((size_t)q*64 + m0 + r)*8;
    for (int kc = 0; kc < 32; ++kc){
      short8 w = ldw8(wp + kc*32);
      acc = MFMA(*(const short8*)(xp + (size_t)kc*2048), w, acc);
    }
  }
  if (W2){
    const float* wp = W2 + (size_t)grow*1024 + q*8;
    const u16* xp = xb + ((size_t)q*64 + m0 + r)*8;
    for (int kc = 0; kc < 32; ++kc){
      short8 w = ldw8(wp + kc*32);
      acc = MFMA(*(const short8*)(xp + (size_t)kc*2048), w, acc);
    }
  }
  float v[4], vf[4], vg[4], vo[4];
#pragma unroll
  for (int i = 0; i < 4; ++i){
    const int brow = m0 + q*4 + i;
    float x = acc[i];
    if (gadd17) x += gadd17[brow*17 + r];
    if (bias16) x += bias16[r];
    v[i] = x;
  }
#pragma unroll
  for (int i = 0; i < 4; ++i){
    vf[i] = __shfl_xor(v[i], 4, 64);
    vg[i] = __shfl_xor(v[i], 8, 64);
    vo[i] = __shfl_xor(v[i], 12, 64);
  }
  if (r < 4){
#pragma unroll
    for (int i = 0; i < 4; ++i){
      const int brow = m0 + q*4 + i;
      float c = sigm(vf[i])*cstL[r*64 + brow] + sigm(v[i])*tanh_(vg[i]);
      const float h = sigm(vo[i])*tanh_(c);
      cstL[r*64 + brow] = c;
      pack16[brow*4 + r] = f2bf(h);
    }
  }
}

__global__ void init_kernel(const float* latent, char* ws){
  const int i = blockIdx.x*blockDim.x + threadIdx.x;  /* 65536 threads */
  if (i < 256) ((u32*)(ws + WS_FLAGS))[i] = 0u;
  if (i < 26624) ((u32*)(ws + WS_NOTE))[i] = 0u;                    /* both note parities */
  if (i < 65536){ ((u32*)(ws + WS_HC0))[i] = 0u; ((u32*)(ws + WS_HC1))[i] = 0u; }
  if (i < 32768){
    const int b = i >> 9, k = i & 511;
    ((u16*)(ws + WS_LAT))[((size_t)(k >> 3)*64 + b)*8 + (k & 7)] = f2bf(latent[i]);
  }
}

__global__ void __launch_bounds__(256, 1) decoder_kernel(Params P){
  extern __shared__ char smem[];
  const int wg = blockIdx.x, tid = threadIdx.x;
  const int lane = tid & 63, wid = tid >> 6;

  u32* flags = (u32*)(P.ws + WS_FLAGS);
  u16* noteb = (u16*)(P.ws + WS_NOTE);
  u16* hd0b  = (u16*)(P.ws + WS_HD0);
  u16* hd1b  = (u16*)(P.ws + WS_HD1);
  u16* hc0b  = (u16*)(P.ws + WS_HC0);
  u16* hc1b  = (u16*)(P.ws + WS_HC1);
  u16* embA  = (u16*)(P.ws + WS_EMB);
  const u16* latg = (const u16*)(P.ws + WS_LAT);

  float* g_sc  = (float*)(smem + L_GSC);
  float* g_c0x = (float*)(smem + L_GC0X);
  float* cc0   = (float*)(smem + L_CC0);
  float* cc1   = (float*)(smem + L_CC1);
  float* bc1   = (float*)(smem + L_BC1);
  u16*   pack16 = (u16*)(smem + L_PACK);
  u32*   packU32 = (u32*)(smem + L_PACK);
  u16*   Wd0  = (u16*)(smem + L_WD0);
  float* g0e  = (float*)(smem + L_G0E);
  float* cst0 = (float*)(smem + L_CST0);
  float* bd0  = (float*)(smem + L_BD0);
  u16*   Wpj  = (u16*)(smem + L_WPJ);
  float* bpj  = (float*)(smem + L_BPJ);
  u16*   Wd1  = (u16*)(smem + L_WD1);
  float* cst1 = (float*)(smem + L_CST1);
  float* bd1  = (float*)(smem + L_BD1);

  const bool is_d0 = (wg < 128);

  /* ---------------- prologue: stage weights into LDS ---------------- */
  if (is_d0){
    for (int r = wid; r < 32; r += 4){
      const int grow = ((r >> 3) << 10) + 8*wg + (r & 7);
      const float* wih = P.Wih_d0 + (size_t)grow*901;
      const float* whh = P.Whh_d0 + (size_t)grow*1024;
      u16* dst = Wd0 + (size_t)r*KD0;
      for (int c = lane; c < 416; c += 64) dst[c] = (c < 389) ? f2bf(wih[c]) : (u16)0;
      for (int c = lane; c < 1024; c += 64) dst[416 + c] = f2bf(whh[c]);
    }
    if (tid < 32){
      const int grow = ((tid >> 3) << 10) + 8*wg + (tid & 7);
      bd0[tid] = P.bih_d0[grow] + P.bhh_d0[grow];
    }
    if (wg < 25){
      for (int r = wid; r < 16; r += 4){
        const int row = 16*wg + r;
        u16* dst = Wpj + (size_t)r*KPROJ;
        if (row < 389){
          const float* w = P.Wdo + (size_t)row*1024;
          for (int c = lane; c < 1024; c += 64) dst[c] = f2bf(w[c]);
        } else {
          for (int c = lane; c < 1024; c += 64) dst[c] = 0;
        }
      }
      if (tid < 16){
        const int row = 16*wg + tid;
        bpj[tid] = (row < 389) ? P.bdo[row] : 0.f;
      }
    }
  } else {
    const int wl = wg - 128;
    for (int r = wid; r < 32; r += 4){
      const int grow = ((r >> 3) << 10) + 8*wl + (r & 7);
      const float* wih = P.Wih_d1 + (size_t)grow*1024;
      const float* whh = P.Whh_d1 + (size_t)grow*1024;
      u16* dst = Wd1 + (size_t)r*KD1;
      for (int c = lane; c < 1024; c += 64) dst[c] = f2bf(wih[c]);
      for (int c = lane; c < 1024; c += 64) dst[1024 + c] = f2bf(whh[c]);
    }
    if (tid < 32){
      const int grow = ((tid >> 3) << 10) + 8*wl + (tid & 7);
      bd1[tid] = P.bih_d1[grow] + P.bhh_d1[grow];
    }
  }
  if (tid < 256){ cc0[tid] = 0.f; cc1[tid] = 0.f; }
  if (tid < 16){
    const int grow = ((tid >> 2) << 10) + 4*wg + (tid & 3);
    bc1[tid] = P.bih_c1[grow] + P.bhh_c1[grow];
  }
  /* g_c0x = latent @ Wih_c0^T + biases; [64][17] f32 */
  {
    const int r = lane & 15, q = lane >> 4, m0 = wid*16;
    const int grow = ((r >> 2) << 10) + 4*wg + (r & 3);
    const float* wp = P.Wih_c0 + (size_t)grow*512 + q*8;
    const u16* xp = latg + ((size_t)q*64 + m0 + r)*8;
    f32x4 acc = {0.f,0.f,0.f,0.f};
    for (int kc = 0; kc < 16; ++kc){
      short8 w = ldw8(wp + kc*32);
      acc = MFMA(*(const short8*)(xp + (size_t)kc*2048), w, acc);
    }
    const float bias = P.bih_c0[grow] + P.bhh_c0[grow];
#pragma unroll
    for (int i = 0; i < 4; ++i)
      g_c0x[(m0 + q*4 + i)*17 + r] = acc[i] + bias;
  }
  __syncthreads();

  u32 ep = 0;

  /* ---------------- conductor: 16 sequential steps ---------------- */
  for (int s = 0; s < 16; ++s){
    const int pc = s & 1;
    const u16* hc0_p = hc0b + (size_t)pc*HC_PAR;
    u16*       hc0_n = hc0b + (size_t)(pc ^ 1)*HC_PAR;
    const u16* hc1_p = hc1b + (size_t)pc*HC_PAR;
    u16*       hc1_n = hc1b + (size_t)(pc ^ 1)*HC_PAR;

    cond_gr(P.Whh_c0, nullptr, hc0_p, nullptr, g_c0x, nullptr, cc0, pack16, 4*wg, lane, wid);
    __syncthreads();
    if (tid < 64){
      u32x2 v = *(const u32x2*)&packU32[tid*2];
      gst2(hc0_n + ((size_t)(wg >> 1)*64 + tid)*8 + (wg & 1)*4, v);
    }
    gbar(flags, wg, ++ep);

    cond_gr(P.Wih_c1, P.Whh_c1, hc0_n, hc1_p, nullptr, bc1, cc1, pack16, 4*wg, lane, wid);
    __syncthreads();
    if (tid < 64){
      u32x2 v = *(const u32x2*)&packU32[tid*2];
      gst2(hc1_n + ((size_t)(wg >> 1)*64 + tid)*8 + (wg & 1)*4, v);
    }
    gbar(flags, wg, ++ep);

    if (wg < 32){
      /* emb cols 16wg..16wg+15 -> granules 2wg, 2wg+1 of embA[s] */
      const int r = lane & 15, q = lane >> 4, m0 = wid*16;
      const int row = 16*wg + r;
      const float* wp = P.Wco + (size_t)row*1024 + q*8;
      const u16* xp = hc1_n + ((size_t)q*64 + m0 + r)*8;
      f32x4 acc = {0.f,0.f,0.f,0.f};
      for (int kc = 0; kc < 32; ++kc){
        short8 w = ldw8(wp + kc*32);
        acc = MFMA(*(const short8*)(xp + (size_t)kc*2048), w, acc);
      }
      const float bias = P.bco[row];
#pragma unroll
      for (int i = 0; i < 4; ++i)
        pack16[(m0 + q*4 + i)*16 + r] = f2bf(tanh_(acc[i] + bias));
      __syncthreads();
      if (tid < 64){
        u16* ea = embA + (size_t)s*EMB_S;
        u32x4 v0 = *(const u32x4*)&packU32[tid*8];
        u32x4 v1 = *(const u32x4*)&packU32[tid*8 + 4];
        gst4(ea + ((size_t)(2*wg)*64 + tid)*8, v0);
        gst4(ea + ((size_t)(2*wg + 1)*64 + tid)*8, v1);
      }
    }
    gbar(flags, wg, ++ep);
  }

  /* ---------------- decoder: 16 subsequences x 32 steps ---------------- */
  for (int s = 0; s < 16; ++s){
    /* subsequence init: h/c inits (granule-packed h flush) + g0e precompute */
    if (is_d0){
      {
        const int b = tid & 63, k = tid >> 6;
        const size_t src = ((size_t)(s*2 + 0)*64 + b)*1024 + 8*wg + 2*k;
        cst0[(2*k)*64 + b]     = P.c0_dec[src];
        cst0[(2*k + 1)*64 + b] = P.c0_dec[src + 1];
        packU32[b*4 + k] = (u32)f2bf(P.h0_dec[src]) | ((u32)f2bf(P.h0_dec[src + 1]) << 16);
      }
      __syncthreads();
      if (tid < 64){
        u32x4 v = *(const u32x4*)&packU32[tid*4];
        gst4(hd0b + ((size_t)wg*64 + tid)*8, v);   /* parity 0 */
      }
      /* g0e = emb[s] @ Wemb^T + bd0 ; Wemb streamed fp32 from HBM (cols 389..900) */
      {
        const int mh = wid & 1, nh = wid >> 1;
        const int q = lane >> 4, rr = lane & 15;
        const int n = nh*16 + rr;
        const int grow = ((n >> 3) << 10) + 8*wg + (n & 7);
        const float* wp = P.Wih_d0 + (size_t)grow*901 + 389 + q*8;
        const u16* ea = embA + (size_t)s*EMB_S;
        const u16* a0 = ea + ((size_t)q*64 + mh*32 + rr)*8;
        const u16* a1 = a0 + 128;
        f32x4 acc0 = {0.f,0.f,0.f,0.f}, acc1 = {0.f,0.f,0.f,0.f};
        for (int kc = 0; kc < 16; ++kc){
          short8 w = ldw8(wp + kc*32);
          acc0 = MFMA(*(const short8*)(a0 + (size_t)kc*2048), w, acc0);
          acc1 = MFMA(*(const short8*)(a1 + (size_t)kc*2048), w, acc1);
        }
        const int r0 = mh*32 + q*4;
        const float bias = bd0[n];
#pragma unroll
        for (int i = 0; i < 4; ++i){
          g0e[(r0 + i)*33 + n]      = acc0[i] + bias;
          g0e[(r0 + 16 + i)*33 + n] = acc1[i] + bias;
        }
      }
    } else {
      const int wl = wg - 128;
      const int b = tid & 63, k = tid >> 6;
      const size_t src = ((size_t)(s*2 + 1)*64 + b)*1024 + 8*wl + 2*k;
      cst1[(2*k)*64 + b]     = P.c0_dec[src];
      cst1[(2*k + 1)*64 + b] = P.c0_dec[src + 1];
      packU32[b*4 + k] = (u32)f2bf(P.h0_dec[src]) | ((u32)f2bf(P.h0_dec[src + 1]) << 16);
      __syncthreads();
      if (tid < 64){
        u32x4 v = *(const u32x4*)&packU32[tid*4];
        gst4(hd1b + ((size_t)wl*64 + tid)*8, v);   /* parity 0 */
      }
    }
    gbar(flags, wg, ++ep);

    for (int t = 0; t < 32; ++t){
      const int p = t & 1;
      const u16* note_p = noteb + (size_t)p*NOTE_PAR;
      u16*       note_n = noteb + (size_t)(p ^ 1)*NOTE_PAR;
      const u16* hd0_p = hd0b + (size_t)p*HD_PAR;
      u16*       hd0_n = hd0b + (size_t)(p ^ 1)*HD_PAR;
      const u16* hd1_p = hd1b + (size_t)p*HD_PAR;
      u16*       hd1_n = hd1b + (size_t)(p ^ 1)*HD_PAR;

      /* phase 1: d0 */
      if (is_d0){
        stage_gr(Wd0, KD0, note_p, 13, hd0_p, 32, 416, g_sc, lane, wid);
        __syncthreads();
        cell_pw(g_sc, g0e, nullptr, cst0, packU32, tid);
        __syncthreads();
        if (tid < 64){
          u32x4 v = *(const u32x4*)&packU32[tid*4];
          gst4(hd0_n + ((size_t)wg*64 + tid)*8, v);
        }
      }
      gbar(flags, wg, ++ep);

      /* phase 2: d1 */
      if (!is_d0){
        stage_gr(Wd1, KD1, hd0_n, 32, hd1_p, 32, 1024, g_sc, lane, wid);
        __syncthreads();
        cell_pw(g_sc, nullptr, bd1, cst1, packU32, tid);
        __syncthreads();
        if (tid < 64){
          u32x4 v = *(const u32x4*)&packU32[tid*4];
          gst4(hd1_n + ((size_t)(wg - 128)*64 + tid)*8, v);
        }
      }
      gbar(flags, wg, ++ep);

      /* phase 3: proj (25 WGs x 16 rows, on d0 CUs) */
      if (wg < 25){
        const int r = lane & 15, q = lane >> 4, m0 = wid*16;
        const u16* wp = Wpj + (size_t)r*KPROJ + q*8;
        const u16* xp = hd1_n + ((size_t)q*64 + m0 + r)*8;
        f32x4 acc = {0.f,0.f,0.f,0.f};
#pragma unroll 4
        for (int kc = 0; kc < 32; ++kc){
          acc = MFMA(*(const short8*)(xp + (size_t)kc*2048),
                     *(const short8*)(wp + kc*32), acc);
        }
        const int row = 16*wg + r;
        const int seq = s*32 + t;
        const float bias = bpj[r];
#pragma unroll
        for (int i = 0; i < 4; ++i){
          const int brow = m0 + q*4 + i;
          const float nv = tanh_(acc[i] + bias);
          if (row < 389) P.out[((size_t)brow*512 + seq)*389 + row] = nv;
          pack16[brow*16 + r] = f2bf(nv);
        }
        __syncthreads();
        if (tid < 64){
          u32x4 v0 = *(const u32x4*)&packU32[tid*8];
          u32x4 v1 = *(const u32x4*)&packU32[tid*8 + 4];
          gst4(note_n + ((size_t)(2*wg)*64 + tid)*8, v0);
          gst4(note_n + ((size_t)(2*wg + 1)*64 + tid)*8, v1);
        }
      }
      gbar(flags, wg, ++ep);
    }
  }
}

extern "C" void kernel_launch(void* const* d_in, const int* in_sizes, int n_in,
                              void* d_out, int out_size, void* d_ws, size_t ws_size,
                              hipStream_t stream){
  (void)in_sizes; (void)n_in; (void)out_size;
  if (ws_size < (size_t)WS_END) return;

  Params P;
  P.latent = (const float*)d_in[0];
  P.h0_dec = (const float*)d_in[3];
  P.c0_dec = (const float*)d_in[4];
  P.Wih_c0 = (const float*)d_in[5];  P.Whh_c0 = (const float*)d_in[6];
  P.bih_c0 = (const float*)d_in[7];  P.bhh_c0 = (const float*)d_in[8];
  P.Wih_c1 = (const float*)d_in[9];  P.Whh_c1 = (const float*)d_in[10];
  P.bih_c1 = (const float*)d_in[11]; P.bhh_c1 = (const float*)d_in[12];
  P.Wco    = (const float*)d_in[13]; P.bco    = (const float*)d_in[14];
  P.Wih_d0 = (const float*)d_in[15]; P.Whh_d0 = (const float*)d_in[16];
  P.bih_d0 = (const float*)d_in[17]; P.bhh_d0 = (const float*)d_in[18];
  P.Wih_d1 = (const float*)d_in[19]; P.Whh_d1 = (const float*)d_in[20];
  P.bih_d1 = (const float*)d_in[21]; P.bhh_d1 = (const float*)d_in[22];
  P.Wdo    = (const float*)d_in[23]; P.bdo    = (const float*)d_in[24];
  P.out = (float*)d_out;
  P.ws  = (char*)d_ws;

  hipLaunchKernelGGL(init_kernel, dim3(256), dim3(256), 0, stream,
                     (const float*)d_in[0], (char*)d_ws);

  hipFuncSetAttribute(reinterpret_cast<const void*>(&decoder_kernel),
                      hipFuncAttributeMaxDynamicSharedMemorySize, LDS_BYTES);
  hipLaunchKernelGGL(decoder_kernel, dim3(NWG), dim3(256), LDS_BYTES, stream, P);
}

// Round 5
// 13942.920 us; speedup vs baseline: 5.9804x; 2.3615x over previous
//
#include <hip/hip_runtime.h>
#include <hip/hip_bf16.h>

typedef unsigned int  u32;
typedef unsigned short u16;
typedef __attribute__((ext_vector_type(8))) short short8;
typedef __attribute__((ext_vector_type(4))) float f32x4;
typedef __attribute__((ext_vector_type(4))) unsigned int u32x4;
typedef __attribute__((ext_vector_type(2))) unsigned int u32x2;

#define MFMA(a,b,c) __builtin_amdgcn_mfma_f32_16x16x32_bf16(a,b,c,0,0,0)

#define NWG    256
#define KD0    1448   /* 416 + 1024 + 8 pad */
#define KD1    2056   /* 2048 + 8 pad */
#define KPROJ  1032   /* 1024 + 8 pad */

/* ---- workspace layout (bytes). granule layout: [K/8 granules][64 b][8 units] u16 ---- */
#define WS_FLAGS 0
#define WS_NOTE  4096
#define WS_HD0   (WS_NOTE + 2*52*64*8*2)
#define WS_HD1   (WS_HD0 + 2*128*64*8*2)
#define WS_HC0   (WS_HD1 + 2*128*64*8*2)
#define WS_HC1   (WS_HC0 + 2*128*64*8*2)
#define WS_EMB   (WS_HC1 + 2*128*64*8*2)
#define WS_LAT   (WS_EMB + 15*64*64*8*2)   /* overlay embA[15]; dead after prologue */
#define WS_END   (WS_EMB + 16*64*64*8*2)

#define NOTE_PAR 26624
#define HD_PAR   65536
#define HC_PAR   65536
#define EMB_S    32768

/* ---- LDS layout (bytes) ---- */
#define L_GSC   0
#define L_GC0X  8448
#define L_CC0   12800
#define L_CC1   13824
#define L_BC1   14848
#define L_PACK  14912
#define L_ROLE  16960
#define L_WD0   L_ROLE
#define L_G0E   (L_ROLE + 32*KD0*2)
#define L_CST0  (L_G0E + 8448)
#define L_BD0   (L_CST0 + 2048)
#define L_WPJ   (L_BD0 + 128)
#define L_BPJ   (L_WPJ + 16*KPROJ*2)
#define L_WD1   L_ROLE
#define L_CST1  (L_ROLE + 32*KD1*2)
#define L_BD1   (L_CST1 + 2048)
#define LDS_BYTES 153600

__device__ __forceinline__ u16 f2bf(float f){
  u32 u = __float_as_uint(f);
  u32 r = (u + 0x7FFFu + ((u >> 16) & 1u)) >> 16;
  return (u16)r;
}
__device__ __forceinline__ float sigm(float x){ return 1.f/(1.f + __expf(-x)); }
__device__ __forceinline__ float tanh_(float x){
  float e = __expf(-2.f*fabsf(x));
  float t = (1.f - e)/(1.f + e);
  return x < 0.f ? -t : t;
}
__device__ __forceinline__ short8 ldw8(const float* p0){
  short8 r;
#pragma unroll
  for (int j = 0; j < 8; ++j) r[j] = (short)f2bf(p0[j]);
  return r;
}

/* ---- sc1 memory ops (coherent at IF; no cache maintenance anywhere) ---- */
__device__ __forceinline__ void gst1(u32* p, u32 v){
  asm volatile("global_store_dword %0, %1, off sc1" :: "v"(p), "v"(v) : "memory");
}
__device__ __forceinline__ void gst4(u16* p, u32x4 v){
  asm volatile("global_store_dwordx4 %0, %1, off sc1" :: "v"(p), "v"(v) : "memory");
}
__device__ __forceinline__ u32x4 ld4_sc1(const u32* p){
  u32x4 v;
  asm volatile("global_load_dwordx4 %0, %1, off sc1\n\ts_waitcnt vmcnt(0)"
               : "=v"(v) : "v"(p) : "memory");
  return v;
}

#define AISSUE(dst, addr) \
  asm volatile("global_load_dwordx4 %0, %1, off sc1" : "=&v"(dst) : "v"(addr) : "memory")
#define AWAITN(cnt) do{ \
  asm volatile("s_waitcnt vmcnt(" #cnt ")" ::: "memory"); \
  __builtin_amdgcn_sched_barrier(0x3F7); }while(0)

/* pipelined M4N1 GEMM core: A from global (sc1, 16-deep ring), B from LDS.
   Per lane: A row = m0+rr, k = q*8 + kc*32. Wl = W + rr*ldw + q*8 (u16). */
template<int NA, int NB, bool TWO>
__device__ __forceinline__ void mm_lds(
    const u16* Wl, int ldw16, const u16* xal, const u16* xbl,
    f32x4& a0, f32x4& a1)
{
  constexpr int N = NA + NB;
  static_assert(N >= 16, "pipe depth");
  short8 ab[16];
#define XADDR(i) (((i) < NA) ? (xal + (size_t)(i)*2048) : (xbl + (size_t)((i)-NA)*2048))
#define ACONS(i) { \
    a0 = MFMA(ab[(i)&15], *(const short8*)(Wl + (size_t)(i)*32), a0); \
    if constexpr (TWO) a1 = MFMA(ab[(i)&15], *(const short8*)(Wl + ldw16 + (size_t)(i)*32), a1); }
#pragma unroll
  for (int i = 0; i < 16; ++i) AISSUE(ab[i], XADDR(i));
#pragma unroll
  for (int i = 0; i < N - 16; ++i){
    AWAITN(15);
    ACONS(i);
    AISSUE(ab[i & 15], XADDR(i + 16));
  }
#define ATAIL(j, c) AWAITN(c); ACONS(N - 16 + (j));
  ATAIL(0,15) ATAIL(1,14) ATAIL(2,13) ATAIL(3,12)
  ATAIL(4,11) ATAIL(5,10) ATAIL(6,9)  ATAIL(7,8)
  ATAIL(8,7)  ATAIL(9,6)  ATAIL(10,5) ATAIL(11,4)
  ATAIL(12,3) ATAIL(13,2) ATAIL(14,1) ATAIL(15,0)
#undef ATAIL
#undef ACONS
#undef XADDR
}

/* batch-16 drain-0 variant: B built from global fp32 via ldw8 (conductor paths).
   (counted waits unsafe here: compiler's plain loads share vmcnt) */
template<int NA, int NB, bool TWO>
__device__ __forceinline__ void mm_gw(
    const float* w00, const float* w01, const float* w10, const float* w11,
    const u16* xal, const u16* xbl, f32x4& a0, f32x4& a1)
{
  constexpr int N = NA + NB;
  static_assert((N % 16) == 0, "");
  short8 ab[16];
#define XADDR(i) (((i) < NA) ? (xal + (size_t)(i)*2048) : (xbl + (size_t)((i)-NA)*2048))
#pragma unroll
  for (int b = 0; b < N/16; ++b){
#pragma unroll
    for (int j = 0; j < 16; ++j) AISSUE(ab[j], XADDR(b*16 + j));
    AWAITN(0);
#pragma unroll
    for (int j = 0; j < 16; ++j){
      const int i = b*16 + j;
      const float* wp0 = (i < NA) ? (w00 + (size_t)i*32) : (w01 + (size_t)(i-NA)*32);
      a0 = MFMA(ab[j], ldw8(wp0), a0);
      if constexpr (TWO){
        const float* wp1 = (i < NA) ? (w10 + (size_t)i*32) : (w11 + (size_t)(i-NA)*32);
        a1 = MFMA(ab[j], ldw8(wp1), a1);
      }
    }
  }
#undef XADDR
}

/* grid barrier: no fences, no invalidates. flags via sc1 only. */
__device__ __forceinline__ void gbar(u32* flags, int wg, u32 ep){
  asm volatile("s_waitcnt vmcnt(0)" ::: "memory");
  __syncthreads();
  if (threadIdx.x < 64){
    const int lane = threadIdx.x;
    if (lane == 0) gst1(&flags[wg], ep);
    for (;;){
      u32x4 f = ld4_sc1(&flags[lane*4]);
      u32 a = f[0] < f[1] ? f[0] : f[1];
      u32 b = f[2] < f[3] ? f[2] : f[3];
      u32 m = a < b ? a : b;
#pragma unroll
      for (int off = 32; off; off >>= 1){
        u32 o = (u32)__shfl_xor((int)m, off, 64);
        m = o < m ? o : m;
      }
      if (m >= ep) break;
      __builtin_amdgcn_s_sleep(1);
    }
  }
  __syncthreads();
}

struct Params {
  const float *latent, *h0_dec, *c0_dec;
  const float *Wih_c0, *Whh_c0, *bih_c0, *bhh_c0;
  const float *Wih_c1, *Whh_c1, *bih_c1, *bhh_c1;
  const float *Wco, *bco;
  const float *Wih_d0, *Whh_d0, *bih_d0, *bhh_d0;
  const float *Wih_d1, *Whh_d1, *bih_d1, *bhh_d1;
  const float *Wdo, *bdo;
  float* out;
  char* ws;
};

/* LSTM pointwise -> packed bf16 pair into LDS pack[64][4] u32 */
__device__ __forceinline__ void cell_pw(
    const float* g_sc, const float* gadd, const float* bias,
    float* cst, u32* pack, int tid)
{
  const int b = tid & 63, k = tid >> 6;
  u32 hp = 0;
#pragma unroll
  for (int j = 0; j < 2; ++j){
    const int u = 2*k + j;
    float gi = g_sc[b*33 + u];
    float gf = g_sc[b*33 + 8 + u];
    float gg = g_sc[b*33 + 16 + u];
    float go = g_sc[b*33 + 24 + u];
    if (gadd){
      gi += gadd[b*33 + u];      gf += gadd[b*33 + 8 + u];
      gg += gadd[b*33 + 16 + u]; go += gadd[b*33 + 24 + u];
    }
    if (bias){
      gi += bias[u]; gf += bias[8 + u]; gg += bias[16 + u]; go += bias[24 + u];
    }
    float c = sigm(gf)*cst[u*64 + b] + sigm(gi)*tanh_(gg);
    const float h = sigm(go)*tanh_(c);
    cst[u*64 + b] = c;
    hp |= ((u32)f2bf(h)) << (16*j);
  }
  pack[b*4 + k] = hp;
}

/* conductor pointwise: 16 gate-rows (4 units x 4 gates) -> pack16[64][4] */
__device__ __forceinline__ void cond_pw(
    f32x4 acc, const float* gadd17, const float* bias16,
    float* cstL, u16* pack16, int lane, int wid)
{
  const int r = lane & 15, q = lane >> 4, m0 = wid*16;
  float v[4], vf[4], vg[4], vo[4];
#pragma unroll
  for (int i = 0; i < 4; ++i){
    const int brow = m0 + q*4 + i;
    float x = acc[i];
    if (gadd17) x += gadd17[brow*17 + r];
    if (bias16) x += bias16[r];
    v[i] = x;
  }
#pragma unroll
  for (int i = 0; i < 4; ++i){
    vf[i] = __shfl_xor(v[i], 4, 64);
    vg[i] = __shfl_xor(v[i], 8, 64);
    vo[i] = __shfl_xor(v[i], 12, 64);
  }
  if (r < 4){
#pragma unroll
    for (int i = 0; i < 4; ++i){
      const int brow = m0 + q*4 + i;
      float c = sigm(vf[i])*cstL[r*64 + brow] + sigm(v[i])*tanh_(vg[i]);
      const float h = sigm(vo[i])*tanh_(c);
      cstL[r*64 + brow] = c;
      pack16[brow*4 + r] = f2bf(h);
    }
  }
}

__global__ void init_kernel(const float* latent, char* ws){
  const int i = blockIdx.x*blockDim.x + threadIdx.x;
  if (i < 256) ((u32*)(ws + WS_FLAGS))[i] = 0u;
  if (i < 26624) ((u32*)(ws + WS_NOTE))[i] = 0u;
  if (i < 65536){ ((u32*)(ws + WS_HC0))[i] = 0u; ((u32*)(ws + WS_HC1))[i] = 0u; }
  if (i < 32768){
    const int b = i >> 9, k = i & 511;
    ((u16*)(ws + WS_LAT))[((size_t)(k >> 3)*64 + b)*8 + (k & 7)] = f2bf(latent[i]);
  }
}

__global__ void __launch_bounds__(256, 1) decoder_kernel(Params P){
  extern __shared__ char smem[];
  const int wg = blockIdx.x, tid = threadIdx.x;
  const int lane = tid & 63, wid = tid >> 6;
  const int rr = lane & 15, q = lane >> 4, m0 = wid*16;

  u32* flags = (u32*)(P.ws + WS_FLAGS);
  u16* noteb = (u16*)(P.ws + WS_NOTE);
  u16* hd0b  = (u16*)(P.ws + WS_HD0);
  u16* hd1b  = (u16*)(P.ws + WS_HD1);
  u16* hc0b  = (u16*)(P.ws + WS_HC0);
  u16* hc1b  = (u16*)(P.ws + WS_HC1);
  u16* embA  = (u16*)(P.ws + WS_EMB);
  const u16* latg = (const u16*)(P.ws + WS_LAT);

  float* g_sc  = (float*)(smem + L_GSC);
  float* g_c0x = (float*)(smem + L_GC0X);
  float* cc0   = (float*)(smem + L_CC0);
  float* cc1   = (float*)(smem + L_CC1);
  float* bc1   = (float*)(smem + L_BC1);
  u16*   pack16 = (u16*)(smem + L_PACK);
  u32*   packU32 = (u32*)(smem + L_PACK);
  u16*   Wd0  = (u16*)(smem + L_WD0);
  float* g0e  = (float*)(smem + L_G0E);
  float* cst0 = (float*)(smem + L_CST0);
  float* bd0  = (float*)(smem + L_BD0);
  u16*   Wpj  = (u16*)(smem + L_WPJ);
  float* bpj  = (float*)(smem + L_BPJ);
  u16*   Wd1  = (u16*)(smem + L_WD1);
  float* cst1 = (float*)(smem + L_CST1);
  float* bd1  = (float*)(smem + L_BD1);

  const bool is_d0 = (wg < 128);
  const int lofs = (q*64 + m0 + rr)*8;   /* lane offset into granule arrays */

  /* ---------------- prologue: stage weights into LDS ---------------- */
  if (is_d0){
    for (int r = wid; r < 32; r += 4){
      const int grow = ((r >> 3) << 10) + 8*wg + (r & 7);
      const float* wih = P.Wih_d0 + (size_t)grow*901;
      const float* whh = P.Whh_d0 + (size_t)grow*1024;
      u16* dst = Wd0 + (size_t)r*KD0;
      for (int c = lane; c < 416; c += 64) dst[c] = (c < 389) ? f2bf(wih[c]) : (u16)0;
      for (int c = lane; c < 1024; c += 64) dst[416 + c] = f2bf(whh[c]);
    }
    if (tid < 32){
      const int grow = ((tid >> 3) << 10) + 8*wg + (tid & 7);
      bd0[tid] = P.bih_d0[grow] + P.bhh_d0[grow];
    }
    if (wg < 25){
      for (int r = wid; r < 16; r += 4){
        const int row = 16*wg + r;
        u16* dst = Wpj + (size_t)r*KPROJ;
        if (row < 389){
          const float* w = P.Wdo + (size_t)row*1024;
          for (int c = lane; c < 1024; c += 64) dst[c] = f2bf(w[c]);
        } else {
          for (int c = lane; c < 1024; c += 64) dst[c] = 0;
        }
      }
      if (tid < 16){
        const int row = 16*wg + tid;
        bpj[tid] = (row < 389) ? P.bdo[row] : 0.f;
      }
    }
  } else {
    const int wl = wg - 128;
    for (int r = wid; r < 32; r += 4){
      const int grow = ((r >> 3) << 10) + 8*wl + (r & 7);
      const float* wih = P.Wih_d1 + (size_t)grow*1024;
      const float* whh = P.Whh_d1 + (size_t)grow*1024;
      u16* dst = Wd1 + (size_t)r*KD1;
      for (int c = lane; c < 1024; c += 64) dst[c] = f2bf(wih[c]);
      for (int c = lane; c < 1024; c += 64) dst[1024 + c] = f2bf(whh[c]);
    }
    if (tid < 32){
      const int grow = ((tid >> 3) << 10) + 8*wl + (tid & 7);
      bd1[tid] = P.bih_d1[grow] + P.bhh_d1[grow];
    }
  }
  if (tid < 256){ cc0[tid] = 0.f; cc1[tid] = 0.f; }
  if (tid < 16){
    const int grow = ((tid >> 2) << 10) + 4*wg + (tid & 3);
    bc1[tid] = P.bih_c1[grow] + P.bhh_c1[grow];
  }
  /* g_c0x = latent @ Wih_c0^T + biases; [64][17] f32.  K=512 -> 16 steps. */
  {
    const int grow = ((rr >> 2) << 10) + 4*wg + (rr & 3);
    f32x4 acc = {0.f,0.f,0.f,0.f}, dummy;
    mm_gw<16,0,false>(P.Wih_c0 + (size_t)grow*512 + q*8, nullptr, nullptr, nullptr,
                      latg + lofs, latg + lofs, acc, dummy);
    const float bias = P.bih_c0[grow] + P.bhh_c0[grow];
#pragma unroll
    for (int i = 0; i < 4; ++i)
      g_c0x[(m0 + q*4 + i)*17 + rr] = acc[i] + bias;
  }
  __syncthreads();

  u32 ep = 0;

  /* ---------------- conductor: 16 sequential steps ---------------- */
  for (int s = 0; s < 16; ++s){
    const int pc = s & 1;
    const u16* hc0_p = hc0b + (size_t)pc*HC_PAR;
    u16*       hc0_n = hc0b + (size_t)(pc ^ 1)*HC_PAR;
    const u16* hc1_p = hc1b + (size_t)pc*HC_PAR;
    u16*       hc1_n = hc1b + (size_t)(pc ^ 1)*HC_PAR;
    const int grow = ((rr >> 2) << 10) + 4*wg + (rr & 3);

    {
      f32x4 acc = {0.f,0.f,0.f,0.f}, dummy;
      mm_gw<32,0,false>(P.Whh_c0 + (size_t)grow*1024 + q*8, nullptr, nullptr, nullptr,
                        hc0_p + lofs, hc0_p + lofs, acc, dummy);
      cond_pw(acc, g_c0x, nullptr, cc0, pack16, lane, wid);
    }
    __syncthreads();
    if (tid < 64){
      u32x2 v = *(const u32x2*)&packU32[tid*2];
      asm volatile("global_store_dwordx2 %0, %1, off sc1"
                   :: "v"(hc0_n + ((size_t)(wg >> 1)*64 + tid)*8 + (wg & 1)*4), "v"(v) : "memory");
    }
    gbar(flags, wg, ++ep);

    {
      f32x4 acc = {0.f,0.f,0.f,0.f}, dummy;
      mm_gw<32,32,false>(P.Wih_c1 + (size_t)grow*1024 + q*8,
                         P.Whh_c1 + (size_t)grow*1024 + q*8, nullptr, nullptr,
                         hc0_n + lofs, hc1_p + lofs, acc, dummy);
      cond_pw(acc, nullptr, bc1, cc1, pack16, lane, wid);
    }
    __syncthreads();
    if (tid < 64){
      u32x2 v = *(const u32x2*)&packU32[tid*2];
      asm volatile("global_store_dwordx2 %0, %1, off sc1"
                   :: "v"(hc1_n + ((size_t)(wg >> 1)*64 + tid)*8 + (wg & 1)*4), "v"(v) : "memory");
    }
    gbar(flags, wg, ++ep);

    if (wg < 32){
      const int row = 16*wg + rr;
      f32x4 acc = {0.f,0.f,0.f,0.f}, dummy;
      mm_gw<32,0,false>(P.Wco + (size_t)row*1024 + q*8, nullptr, nullptr, nullptr,
                        hc1_n + lofs, hc1_n + lofs, acc, dummy);
      const float bias = P.bco[row];
#pragma unroll
      for (int i = 0; i < 4; ++i)
        pack16[(m0 + q*4 + i)*16 + rr] = f2bf(tanh_(acc[i] + bias));
      __syncthreads();
      if (tid < 64){
        u16* ea = embA + (size_t)s*EMB_S;
        u32x4 v0 = *(const u32x4*)&packU32[tid*8];
        u32x4 v1 = *(const u32x4*)&packU32[tid*8 + 4];
        gst4(ea + ((size_t)(2*wg)*64 + tid)*8, v0);
        gst4(ea + ((size_t)(2*wg + 1)*64 + tid)*8, v1);
      }
    }
    gbar(flags, wg, ++ep);
  }

  /* ---------------- decoder: 16 subsequences x 32 steps ---------------- */
  for (int s = 0; s < 16; ++s){
    if (is_d0){
      {
        const int b = tid & 63, k = tid >> 6;
        const size_t src = ((size_t)(s*2 + 0)*64 + b)*1024 + 8*wg + 2*k;
        cst0[(2*k)*64 + b]     = P.c0_dec[src];
        cst0[(2*k + 1)*64 + b] = P.c0_dec[src + 1];
        packU32[b*4 + k] = (u32)f2bf(P.h0_dec[src]) | ((u32)f2bf(P.h0_dec[src + 1]) << 16);
      }
      __syncthreads();
      if (tid < 64){
        u32x4 v = *(const u32x4*)&packU32[tid*4];
        gst4(hd0b + ((size_t)wg*64 + tid)*8, v);   /* parity 0 */
      }
      /* g0e = emb[s] @ Wemb^T + bd0 (Wemb = Wih_d0 cols 389..900, fp32 from L2) */
      {
        const int g0 = ((rr >> 3) << 10) + 8*wg + (rr & 7);
        const int g1 = (((rr + 16) >> 3) << 10) + 8*wg + (rr & 7);
        f32x4 a0 = {0.f,0.f,0.f,0.f}, a1 = {0.f,0.f,0.f,0.f};
        const u16* ea = embA + (size_t)s*EMB_S;
        mm_gw<16,0,true>(P.Wih_d0 + (size_t)g0*901 + 389 + q*8, nullptr,
                         P.Wih_d0 + (size_t)g1*901 + 389 + q*8, nullptr,
                         ea + lofs, ea + lofs, a0, a1);
#pragma unroll
        for (int i = 0; i < 4; ++i){
          g0e[(m0 + q*4 + i)*33 + rr]      = a0[i] + bd0[rr];
          g0e[(m0 + q*4 + i)*33 + 16 + rr] = a1[i] + bd0[rr + 16];
        }
      }
    } else {
      const int wl = wg - 128;
      const int b = tid & 63, k = tid >> 6;
      const size_t src = ((size_t)(s*2 + 1)*64 + b)*1024 + 8*wl + 2*k;
      cst1[(2*k)*64 + b]     = P.c0_dec[src];
      cst1[(2*k + 1)*64 + b] = P.c0_dec[src + 1];
      packU32[b*4 + k] = (u32)f2bf(P.h0_dec[src]) | ((u32)f2bf(P.h0_dec[src + 1]) << 16);
      __syncthreads();
      if (tid < 64){
        u32x4 v = *(const u32x4*)&packU32[tid*4];
        gst4(hd1b + ((size_t)wl*64 + tid)*8, v);   /* parity 0 */
      }
    }
    gbar(flags, wg, ++ep);

    for (int t = 0; t < 32; ++t){
      const int p = t & 1;
      const u16* note_p = noteb + (size_t)p*NOTE_PAR;
      u16*       note_n = noteb + (size_t)(p ^ 1)*NOTE_PAR;
      const u16* hd0_p = hd0b + (size_t)p*HD_PAR;
      u16*       hd0_n = hd0b + (size_t)(p ^ 1)*HD_PAR;
      const u16* hd1_p = hd1b + (size_t)p*HD_PAR;
      u16*       hd1_n = hd1b + (size_t)(p ^ 1)*HD_PAR;

      /* phase 1: d0 */
      if (is_d0){
        f32x4 a0 = {0.f,0.f,0.f,0.f}, a1 = {0.f,0.f,0.f,0.f};
        mm_lds<13,32,true>(Wd0 + (size_t)rr*KD0 + q*8, 16*KD0,
                           note_p + lofs, hd0_p + lofs, a0, a1);
#pragma unroll
        for (int i = 0; i < 4; ++i){
          g_sc[(m0 + q*4 + i)*33 + rr]      = a0[i];
          g_sc[(m0 + q*4 + i)*33 + 16 + rr] = a1[i];
        }
        __syncthreads();
        cell_pw(g_sc, g0e, nullptr, cst0, packU32, tid);
        __syncthreads();
        if (tid < 64){
          u32x4 v = *(const u32x4*)&packU32[tid*4];
          gst4(hd0_n + ((size_t)wg*64 + tid)*8, v);
        }
      }
      gbar(flags, wg, ++ep);

      /* phase 2: d1 */
      if (!is_d0){
        f32x4 a0 = {0.f,0.f,0.f,0.f}, a1 = {0.f,0.f,0.f,0.f};
        mm_lds<32,32,true>(Wd1 + (size_t)rr*KD1 + q*8, 16*KD1,
                           hd0_n + lofs, hd1_p + lofs, a0, a1);
#pragma unroll
        for (int i = 0; i < 4; ++i){
          g_sc[(m0 + q*4 + i)*33 + rr]      = a0[i];
          g_sc[(m0 + q*4 + i)*33 + 16 + rr] = a1[i];
        }
        __syncthreads();
        cell_pw(g_sc, nullptr, bd1, cst1, packU32, tid);
        __syncthreads();
        if (tid < 64){
          u32x4 v = *(const u32x4*)&packU32[tid*4];
          gst4(hd1_n + ((size_t)(wg - 128)*64 + tid)*8, v);
        }
      }
      gbar(flags, wg, ++ep);

      /* phase 3: proj (25 WGs x 16 rows) */
      if (wg < 25){
        f32x4 a0 = {0.f,0.f,0.f,0.f}, a1;
        mm_lds<32,0,false>(Wpj + (size_t)rr*KPROJ + q*8, 0,
                           hd1_n + lofs, hd1_n + lofs, a0, a1);
        const int row = 16*wg + rr;
        const int seq = s*32 + t;
        const float bias = bpj[rr];
#pragma unroll
        for (int i = 0; i < 4; ++i){
          const int brow = m0 + q*4 + i;
          const float nv = tanh_(a0[i] + bias);
          if (row < 389) P.out[((size_t)brow*512 + seq)*389 + row] = nv;
          pack16[brow*16 + rr] = f2bf(nv);
        }
        __syncthreads();
        if (tid < 64){
          u32x4 v0 = *(const u32x4*)&packU32[tid*8];
          u32x4 v1 = *(const u32x4*)&packU32[tid*8 + 4];
          gst4(note_n + ((size_t)(2*wg)*64 + tid)*8, v0);
          gst4(note_n + ((size_t)(2*wg + 1)*64 + tid)*8, v1);
        }
      }
      gbar(flags, wg, ++ep);
    }
  }
}

extern "C" void kernel_launch(void* const* d_in, const int* in_sizes, int n_in,
                              void* d_out, int out_size, void* d_ws, size_t ws_size,
                              hipStream_t stream){
  (void)in_sizes; (void)n_in; (void)out_size;
  if (ws_size < (size_t)WS_END) return;

  Params P;
  P.latent = (const float*)d_in[0];
  P.h0_dec = (const float*)d_in[3];
  P.c0_dec = (const float*)d_in[4];
  P.Wih_c0 = (const float*)d_in[5];  P.Whh_c0 = (const float*)d_in[6];
  P.bih_c0 = (const float*)d_in[7];  P.bhh_c0 = (const float*)d_in[8];
  P.Wih_c1 = (const float*)d_in[9];  P.Whh_c1 = (const float*)d_in[10];
  P.bih_c1 = (const float*)d_in[11]; P.bhh_c1 = (const float*)d_in[12];
  P.Wco    = (const float*)d_in[13]; P.bco    = (const float*)d_in[14];
  P.Wih_d0 = (const float*)d_in[15]; P.Whh_d0 = (const float*)d_in[16];
  P.bih_d0 = (const float*)d_in[17]; P.bhh_d0 = (const float*)d_in[18];
  P.Wih_d1 = (const float*)d_in[19]; P.Whh_d1 = (const float*)d_in[20];
  P.bih_d1 = (const float*)d_in[21]; P.bhh_d1 = (const float*)d_in[22];
  P.Wdo    = (const float*)d_in[23]; P.bdo    = (const float*)d_in[24];
  P.out = (float*)d_out;
  P.ws  = (char*)d_ws;

  hipLaunchKernelGGL(init_kernel, dim3(256), dim3(256), 0, stream,
                     (const float*)d_in[0], (char*)d_ws);

  hipFuncSetAttribute(reinterpret_cast<const void*>(&decoder_kernel),
                      hipFuncAttributeMaxDynamicSharedMemorySize, LDS_BYTES);
  hipLaunchKernelGGL(decoder_kernel, dim3(NWG), dim3(256), LDS_BYTES, stream, P);
}

// Round 7
// 9247.026 us; speedup vs baseline: 9.0174x; 1.5078x over previous
//
#include <hip/hip_runtime.h>
#include <hip/hip_bf16.h>

typedef unsigned int  u32;
typedef unsigned short u16;
typedef __attribute__((ext_vector_type(8))) short short8;
typedef __attribute__((ext_vector_type(4))) float f32x4;
typedef __attribute__((ext_vector_type(4))) unsigned int u32x4;
typedef __attribute__((ext_vector_type(2))) unsigned int u32x2;

#define MFMA(a,b,c) __builtin_amdgcn_mfma_f32_16x16x32_bf16(a,b,c,0,0,0)

#define NWG    256
#define KD0    1448   /* 416 + 1024 + 8 pad */
#define KD1    2056   /* 2048 + 8 pad */
#define KPROJ  1032   /* 1024 + 8 pad */

/* ---- barrier state (first 4096 B of ws), all signaling at IF via sc1 ---- */
#define WS_ARR   0      /* 8 groups x 32 u32 (128 B per group) */
#define WS_DONE  1024   /* 8 u32: per-group done flags (single line) */

/* ---- workspace layout. granule layout: [K/8 granules][64 b][8 units] u16 ---- */
#define WS_NOTE  4096
#define WS_HD0   (WS_NOTE + 2*52*64*8*2)
#define WS_HD1   (WS_HD0 + 2*128*64*8*2)
#define WS_HC0   (WS_HD1 + 2*128*64*8*2)
#define WS_HC1   (WS_HC0 + 2*128*64*8*2)
#define WS_EMB   (WS_HC1 + 2*128*64*8*2)
#define WS_LAT   (WS_EMB + 15*64*64*8*2)   /* overlay embA[15]; dead after prologue */
#define WS_END   (WS_EMB + 16*64*64*8*2)

#define NOTE_PAR 26624
#define HD_PAR   65536
#define HC_PAR   65536
#define EMB_S    32768

/* ---- LDS layout (bytes) ---- */
#define L_GSC   0
#define L_GC0X  8448
#define L_CC0   12800
#define L_CC1   13824
#define L_BC1   14848
#define L_PACK  14912
#define L_ROLE  16960
#define L_WD0   L_ROLE
#define L_G0E   (L_ROLE + 32*KD0*2)
#define L_CST0  (L_G0E + 8448)
#define L_BD0   (L_CST0 + 2048)
#define L_WPJ   (L_BD0 + 128)
#define L_BPJ   (L_WPJ + 16*KPROJ*2)
#define L_WD1   L_ROLE
#define L_CST1  (L_ROLE + 32*KD1*2)
#define L_BD1   (L_CST1 + 2048)
#define LDS_BYTES 153600

__device__ __forceinline__ u16 f2bf(float f){
  u32 u = __float_as_uint(f);
  u32 r = (u + 0x7FFFu + ((u >> 16) & 1u)) >> 16;
  return (u16)r;
}
__device__ __forceinline__ float sigm(float x){ return 1.f/(1.f + __expf(-x)); }
__device__ __forceinline__ float tanh_(float x){
  float e = __expf(-2.f*fabsf(x));
  float t = (1.f - e)/(1.f + e);
  return x < 0.f ? -t : t;
}
__device__ __forceinline__ short8 ldw8(const float* p0){
  short8 r;
#pragma unroll
  for (int j = 0; j < 8; ++j) r[j] = (short)f2bf(p0[j]);
  return r;
}

/* ---- sc1 (IF-coherent) ops; no cache maintenance anywhere ---- */
__device__ __forceinline__ void gst1(u32* p, u32 v){
  asm volatile("global_store_dword %0, %1, off sc1" :: "v"(p), "v"(v) : "memory");
}
__device__ __forceinline__ void gst4(u16* p, u32x4 v){
  asm volatile("global_store_dwordx4 %0, %1, off sc1" :: "v"(p), "v"(v) : "memory");
}
__device__ __forceinline__ u32 ld1_sc1(const u32* p){
  u32 v;
  asm volatile("global_load_dword %0, %1, off sc1\n\ts_waitcnt vmcnt(0)"
               : "=v"(v) : "v"(p) : "memory");
  return v;
}

#define AISSUE(dst, addr) \
  asm volatile("global_load_dwordx4 %0, %1, off sc1" : "=&v"(dst) : "v"(addr) : "memory")
#define AWAITN(cnt) do{ \
  asm volatile("s_waitcnt vmcnt(" #cnt ")" ::: "memory"); \
  __builtin_amdgcn_sched_barrier(0x3F7); }while(0)

/* pipelined M4N1 GEMM core: A from global (sc1, 16-deep ring), B from LDS. */
template<int NA, int NB, bool TWO>
__device__ __forceinline__ void mm_lds(
    const u16* Wl, int ldw16, const u16* xal, const u16* xbl,
    f32x4& a0, f32x4& a1)
{
  constexpr int N = NA + NB;
  short8 ab[(N < 16) ? N : 16];
#define XADDR(i) (((i) < NA) ? (xal + (size_t)(i)*2048) : (xbl + (size_t)((i)-NA)*2048))
#define ACONS(i) { \
    a0 = MFMA(ab[(i)&15], *(const short8*)(Wl + (size_t)(i)*32), a0); \
    if constexpr (TWO) a1 = MFMA(ab[(i)&15], *(const short8*)(Wl + ldw16 + (size_t)(i)*32), a1); }
  if constexpr (N <= 16){
#pragma unroll
    for (int i = 0; i < N; ++i) AISSUE(ab[i], XADDR(i));
    AWAITN(0);
#pragma unroll
    for (int i = 0; i < N; ++i) ACONS(i);
  } else {
#pragma unroll
    for (int i = 0; i < 16; ++i) AISSUE(ab[i], XADDR(i));
#pragma unroll
    for (int i = 0; i < N - 16; ++i){
      AWAITN(15);
      ACONS(i);
      AISSUE(ab[i & 15], XADDR(i + 16));
    }
#define ATAIL(j, c) AWAITN(c); ACONS(N - 16 + (j));
    ATAIL(0,15) ATAIL(1,14) ATAIL(2,13) ATAIL(3,12)
    ATAIL(4,11) ATAIL(5,10) ATAIL(6,9)  ATAIL(7,8)
    ATAIL(8,7)  ATAIL(9,6)  ATAIL(10,5) ATAIL(11,4)
    ATAIL(12,3) ATAIL(13,2) ATAIL(14,1) ATAIL(15,0)
#undef ATAIL
  }
#undef ACONS
#undef XADDR
}

/* batch-16 drain-0 variant: B built from global fp32 via ldw8 (conductor paths). */
template<int NA, int NB, bool TWO>
__device__ __forceinline__ void mm_gw(
    const float* w00, const float* w01, const float* w10, const float* w11,
    const u16* xal, const u16* xbl, f32x4& a0, f32x4& a1)
{
  constexpr int N = NA + NB;
  static_assert((N % 16) == 0, "");
  short8 ab[16];
#define XADDR(i) (((i) < NA) ? (xal + (size_t)(i)*2048) : (xbl + (size_t)((i)-NA)*2048))
#pragma unroll
  for (int b = 0; b < N/16; ++b){
#pragma unroll
    for (int j = 0; j < 16; ++j) AISSUE(ab[j], XADDR(b*16 + j));
    AWAITN(0);
#pragma unroll
    for (int j = 0; j < 16; ++j){
      const int i = b*16 + j;
      const float* wp0 = (i < NA) ? (w00 + (size_t)i*32) : (w01 + (size_t)(i-NA)*32);
      a0 = MFMA(ab[j], ldw8(wp0), a0);
      if constexpr (TWO){
        const float* wp1 = (i < NA) ? (w10 + (size_t)i*32) : (w11 + (size_t)(i-NA)*32);
        a1 = MFMA(ab[j], ldw8(wp1), a1);
      }
    }
  }
#undef XADDR
}

/* hierarchical grid barrier, IF-only (topology-free):
   member -> group arrive block (1 poller/block) -> leader posts done[grp]
   -> everyone polls the single done[] line (written only 8x/epoch). */
__device__ __forceinline__ void gbar(char* ws, int grp, int mem, u32 ep){
  u32* arr  = (u32*)(ws + WS_ARR) + grp*32;
  u32* done = (u32*)(ws + WS_DONE);
  asm volatile("s_waitcnt vmcnt(0)" ::: "memory");
  __syncthreads();
  if (threadIdx.x < 64){
    const int l = threadIdx.x;
    if (l == 0) gst1(&arr[mem], ep);
    if (mem == 0){
      for (;;){
        u32 m = (l < 32) ? ld1_sc1(&arr[l]) : ep;
#pragma unroll
        for (int off = 32; off; off >>= 1){
          u32 o = (u32)__shfl_xor((int)m, off, 64);
          m = o < m ? o : m;
        }
        if (m >= ep) break;
      }
      if (l == 0) gst1(&done[grp], ep);
    }
    for (;;){
      u32 m = (l < 8) ? ld1_sc1(&done[l]) : ep;
#pragma unroll
      for (int off = 32; off; off >>= 1){
        u32 o = (u32)__shfl_xor((int)m, off, 64);
        m = o < m ? o : m;
      }
      if (m >= ep) break;
      __builtin_amdgcn_s_sleep(1);
    }
  }
  __syncthreads();
}

struct Params {
  const float *latent, *h0_dec, *c0_dec;
  const float *Wih_c0, *Whh_c0, *bih_c0, *bhh_c0;
  const float *Wih_c1, *Whh_c1, *bih_c1, *bhh_c1;
  const float *Wco, *bco;
  const float *Wih_d0, *Whh_d0, *bih_d0, *bhh_d0;
  const float *Wih_d1, *Whh_d1, *bih_d1, *bhh_d1;
  const float *Wdo, *bdo;
  float* out;
  char* ws;
};

/* LSTM pointwise -> packed bf16 pair into LDS pack[64][4] u32 */
__device__ __forceinline__ void cell_pw(
    const float* g_sc, const float* gadd, const float* bias,
    float* cst, u32* pack, int tid)
{
  const int b = tid & 63, k = tid >> 6;
  u32 hp = 0;
#pragma unroll
  for (int j = 0; j < 2; ++j){
    const int u = 2*k + j;
    float gi = g_sc[b*33 + u];
    float gf = g_sc[b*33 + 8 + u];
    float gg = g_sc[b*33 + 16 + u];
    float go = g_sc[b*33 + 24 + u];
    if (gadd){
      gi += gadd[b*33 + u];      gf += gadd[b*33 + 8 + u];
      gg += gadd[b*33 + 16 + u]; go += gadd[b*33 + 24 + u];
    }
    if (bias){
      gi += bias[u]; gf += bias[8 + u]; gg += bias[16 + u]; go += bias[24 + u];
    }
    float c = sigm(gf)*cst[u*64 + b] + sigm(gi)*tanh_(gg);
    const float h = sigm(go)*tanh_(c);
    cst[u*64 + b] = c;
    hp |= ((u32)f2bf(h)) << (16*j);
  }
  pack[b*4 + k] = hp;
}

/* conductor pointwise */
__device__ __forceinline__ void cond_pw(
    f32x4 acc, const float* gadd17, const float* bias16,
    float* cstL, u16* pack16, int lane, int wid)
{
  const int r = lane & 15, q = lane >> 4, m0 = wid*16;
  float v[4], vf[4], vg[4], vo[4];
#pragma unroll
  for (int i = 0; i < 4; ++i){
    const int brow = m0 + q*4 + i;
    float x = acc[i];
    if (gadd17) x += gadd17[brow*17 + r];
    if (bias16) x += bias16[r];
    v[i] = x;
  }
#pragma unroll
  for (int i = 0; i < 4; ++i){
    vf[i] = __shfl_xor(v[i], 4, 64);
    vg[i] = __shfl_xor(v[i], 8, 64);
    vo[i] = __shfl_xor(v[i], 12, 64);
  }
  if (r < 4){
#pragma unroll
    for (int i = 0; i < 4; ++i){
      const int brow = m0 + q*4 + i;
      float c = sigm(vf[i])*cstL[r*64 + brow] + sigm(v[i])*tanh_(vg[i]);
      const float h = sigm(vo[i])*tanh_(c);
      cstL[r*64 + brow] = c;
      pack16[brow*4 + r] = f2bf(h);
    }
  }
}

__global__ void init_kernel(const float* latent, char* ws){
  const int i = blockIdx.x*blockDim.x + threadIdx.x;
  if (i < 1024) ((u32*)ws)[i] = 0u;                 /* all barrier state */
  if (i < 26624) ((u32*)(ws + WS_NOTE))[i] = 0u;
  if (i < 65536){ ((u32*)(ws + WS_HC0))[i] = 0u; ((u32*)(ws + WS_HC1))[i] = 0u; }
  if (i < 32768){
    const int b = i >> 9, k = i & 511;
    ((u16*)(ws + WS_LAT))[((size_t)(k >> 3)*64 + b)*8 + (k & 7)] = f2bf(latent[i]);
  }
}

__global__ void __launch_bounds__(256, 1) decoder_kernel(Params P){
  extern __shared__ char smem[];
  const int wg = blockIdx.x, tid = threadIdx.x;
  const int lane = tid & 63, wid = tid >> 6;
  const int rr = lane & 15, q = lane >> 4, m0 = wid*16;
  const int grp = wg >> 5, mem = wg & 31;

  u16* noteb = (u16*)(P.ws + WS_NOTE);
  u16* hd0b  = (u16*)(P.ws + WS_HD0);
  u16* hd1b  = (u16*)(P.ws + WS_HD1);
  u16* hc0b  = (u16*)(P.ws + WS_HC0);
  u16* hc1b  = (u16*)(P.ws + WS_HC1);
  u16* embA  = (u16*)(P.ws + WS_EMB);
  const u16* latg = (const u16*)(P.ws + WS_LAT);

  float* g_sc  = (float*)(smem + L_GSC);
  float* g_c0x = (float*)(smem + L_GC0X);
  float* cc0   = (float*)(smem + L_CC0);
  float* cc1   = (float*)(smem + L_CC1);
  float* bc1   = (float*)(smem + L_BC1);
  u16*   pack16 = (u16*)(smem + L_PACK);
  u32*   packU32 = (u32*)(smem + L_PACK);
  u16*   Wd0  = (u16*)(smem + L_WD0);
  float* g0e  = (float*)(smem + L_G0E);
  float* cst0 = (float*)(smem + L_CST0);
  float* bd0  = (float*)(smem + L_BD0);
  u16*   Wpj  = (u16*)(smem + L_WPJ);
  float* bpj  = (float*)(smem + L_BPJ);
  u16*   Wd1  = (u16*)(smem + L_WD1);
  float* cst1 = (float*)(smem + L_CST1);
  float* bd1  = (float*)(smem + L_BD1);

  const bool is_d0 = (wg < 128);
  const int lofs = (q*64 + m0 + rr)*8;

  /* ---------------- prologue: stage weights into LDS ---------------- */
  if (is_d0){
    for (int r = wid; r < 32; r += 4){
      const int grow = ((r >> 3) << 10) + 8*wg + (r & 7);
      const float* wih = P.Wih_d0 + (size_t)grow*901;
      const float* whh = P.Whh_d0 + (size_t)grow*1024;
      u16* dst = Wd0 + (size_t)r*KD0;
      for (int c = lane; c < 416; c += 64) dst[c] = (c < 389) ? f2bf(wih[c]) : (u16)0;
      for (int c = lane; c < 1024; c += 64) dst[416 + c] = f2bf(whh[c]);
    }
    if (tid < 32){
      const int grow = ((tid >> 3) << 10) + 8*wg + (tid & 7);
      bd0[tid] = P.bih_d0[grow] + P.bhh_d0[grow];
    }
    if (wg < 25){
      for (int r = wid; r < 16; r += 4){
        const int row = 16*wg + r;
        u16* dst = Wpj + (size_t)r*KPROJ;
        if (row < 389){
          const float* w = P.Wdo + (size_t)row*1024;
          for (int c = lane; c < 1024; c += 64) dst[c] = f2bf(w[c]);
        } else {
          for (int c = lane; c < 1024; c += 64) dst[c] = 0;
        }
      }
      if (tid < 16){
        const int row = 16*wg + tid;
        bpj[tid] = (row < 389) ? P.bdo[row] : 0.f;
      }
    }
  } else {
    const int wl = wg - 128;
    for (int r = wid; r < 32; r += 4){
      const int grow = ((r >> 3) << 10) + 8*wl + (r & 7);
      const float* wih = P.Wih_d1 + (size_t)grow*1024;
      const float* whh = P.Whh_d1 + (size_t)grow*1024;
      u16* dst = Wd1 + (size_t)r*KD1;
      for (int c = lane; c < 1024; c += 64) dst[c] = f2bf(wih[c]);
      for (int c = lane; c < 1024; c += 64) dst[1024 + c] = f2bf(whh[c]);
    }
    if (tid < 32){
      const int grow = ((tid >> 3) << 10) + 8*wl + (tid & 7);
      bd1[tid] = P.bih_d1[grow] + P.bhh_d1[grow];
    }
  }
  if (tid < 256){ cc0[tid] = 0.f; cc1[tid] = 0.f; }
  if (tid < 16){
    const int grow = ((tid >> 2) << 10) + 4*wg + (tid & 3);
    bc1[tid] = P.bih_c1[grow] + P.bhh_c1[grow];
  }
  /* g_c0x = latent @ Wih_c0^T + biases; [64][17] f32.  K=512 -> 16 steps. */
  {
    const int grow = ((rr >> 2) << 10) + 4*wg + (rr & 3);
    f32x4 acc = {0.f,0.f,0.f,0.f}, dummy;
    mm_gw<16,0,false>(P.Wih_c0 + (size_t)grow*512 + q*8, nullptr, nullptr, nullptr,
                      latg + lofs, latg + lofs, acc, dummy);
    const float bias = P.bih_c0[grow] + P.bhh_c0[grow];
#pragma unroll
    for (int i = 0; i < 4; ++i)
      g_c0x[(m0 + q*4 + i)*17 + rr] = acc[i] + bias;
  }
  __syncthreads();

  u32 ep = 0;
#define GBAR() gbar(P.ws, grp, mem, ++ep)

  /* ---------------- conductor: 16 sequential steps ---------------- */
  for (int s = 0; s < 16; ++s){
    const int pc = s & 1;
    const u16* hc0_p = hc0b + (size_t)pc*HC_PAR;
    u16*       hc0_n = hc0b + (size_t)(pc ^ 1)*HC_PAR;
    const u16* hc1_p = hc1b + (size_t)pc*HC_PAR;
    u16*       hc1_n = hc1b + (size_t)(pc ^ 1)*HC_PAR;
    const int grow = ((rr >> 2) << 10) + 4*wg + (rr & 3);

    {
      f32x4 acc = {0.f,0.f,0.f,0.f}, dummy;
      mm_gw<32,0,false>(P.Whh_c0 + (size_t)grow*1024 + q*8, nullptr, nullptr, nullptr,
                        hc0_p + lofs, hc0_p + lofs, acc, dummy);
      cond_pw(acc, g_c0x, nullptr, cc0, pack16, lane, wid);
    }
    __syncthreads();
    if (tid < 64){
      u32x2 v = *(const u32x2*)&packU32[tid*2];
      asm volatile("global_store_dwordx2 %0, %1, off sc1"
                   :: "v"(hc0_n + ((size_t)(wg >> 1)*64 + tid)*8 + (wg & 1)*4), "v"(v) : "memory");
    }
    GBAR();

    {
      f32x4 acc = {0.f,0.f,0.f,0.f}, dummy;
      mm_gw<32,32,false>(P.Wih_c1 + (size_t)grow*1024 + q*8,
                         P.Whh_c1 + (size_t)grow*1024 + q*8, nullptr, nullptr,
                         hc0_n + lofs, hc1_p + lofs, acc, dummy);
      cond_pw(acc, nullptr, bc1, cc1, pack16, lane, wid);
    }
    __syncthreads();
    if (tid < 64){
      u32x2 v = *(const u32x2*)&packU32[tid*2];
      asm volatile("global_store_dwordx2 %0, %1, off sc1"
                   :: "v"(hc1_n + ((size_t)(wg >> 1)*64 + tid)*8 + (wg & 1)*4), "v"(v) : "memory");
    }
    GBAR();

    if (wg < 32){
      const int row = 16*wg + rr;
      f32x4 acc = {0.f,0.f,0.f,0.f}, dummy;
      mm_gw<32,0,false>(P.Wco + (size_t)row*1024 + q*8, nullptr, nullptr, nullptr,
                        hc1_n + lofs, hc1_n + lofs, acc, dummy);
      const float bias = P.bco[row];
#pragma unroll
      for (int i = 0; i < 4; ++i)
        pack16[(m0 + q*4 + i)*16 + rr] = f2bf(tanh_(acc[i] + bias));
      __syncthreads();
      if (tid < 64){
        u16* ea = embA + (size_t)s*EMB_S;
        u32x4 v0 = *(const u32x4*)&packU32[tid*8];
        u32x4 v1 = *(const u32x4*)&packU32[tid*8 + 4];
        gst4(ea + ((size_t)(2*wg)*64 + tid)*8, v0);
        gst4(ea + ((size_t)(2*wg + 1)*64 + tid)*8, v1);
      }
    }
    GBAR();
  }

  /* ---------------- decoder: 16 subsequences x 32 steps ---------------- */
  for (int s = 0; s < 16; ++s){
    /* persistent Whh shadow accumulators (valid from t>=1) */
    f32x4 sh0 = {0.f,0.f,0.f,0.f}, sh1 = sh0;   /* d0: Whh_d0 . hd0(t) */
    f32x4 t10 = sh0, t11 = sh0;                 /* d1: Whh_d1 . hd1(t) */

    if (is_d0){
      {
        const int b = tid & 63, k = tid >> 6;
        const size_t src = ((size_t)(s*2 + 0)*64 + b)*1024 + 8*wg + 2*k;
        cst0[(2*k)*64 + b]     = P.c0_dec[src];
        cst0[(2*k + 1)*64 + b] = P.c0_dec[src + 1];
        packU32[b*4 + k] = (u32)f2bf(P.h0_dec[src]) | ((u32)f2bf(P.h0_dec[src + 1]) << 16);
      }
      __syncthreads();
      if (tid < 64){
        u32x4 v = *(const u32x4*)&packU32[tid*4];
        gst4(hd0b + ((size_t)wg*64 + tid)*8, v);   /* parity 0 */
      }
      /* g0e = emb[s] @ Wemb^T + bd0 (Wemb = Wih_d0 cols 389..900, fp32 from L2) */
      {
        const int g0 = ((rr >> 3) << 10) + 8*wg + (rr & 7);
        const int g1 = (((rr + 16) >> 3) << 10) + 8*wg + (rr & 7);
        f32x4 a0 = {0.f,0.f,0.f,0.f}, a1 = {0.f,0.f,0.f,0.f};
        const u16* ea = embA + (size_t)s*EMB_S;
        mm_gw<16,0,true>(P.Wih_d0 + (size_t)g0*901 + 389 + q*8, nullptr,
                         P.Wih_d0 + (size_t)g1*901 + 389 + q*8, nullptr,
                         ea + lofs, ea + lofs, a0, a1);
#pragma unroll
        for (int i = 0; i < 4; ++i){
          g0e[(m0 + q*4 + i)*33 + rr]      = a0[i] + bd0[rr];
          g0e[(m0 + q*4 + i)*33 + 16 + rr] = a1[i] + bd0[rr + 16];
        }
      }
    } else {
      const int wl = wg - 128;
      const int b = tid & 63, k = tid >> 6;
      const size_t src = ((size_t)(s*2 + 1)*64 + b)*1024 + 8*wl + 2*k;
      cst1[(2*k)*64 + b]     = P.c0_dec[src];
      cst1[(2*k + 1)*64 + b] = P.c0_dec[src + 1];
      packU32[b*4 + k] = (u32)f2bf(P.h0_dec[src]) | ((u32)f2bf(P.h0_dec[src + 1]) << 16);
      __syncthreads();
      if (tid < 64){
        u32x4 v = *(const u32x4*)&packU32[tid*4];
        gst4(hd1b + ((size_t)wl*64 + tid)*8, v);   /* parity 0 */
      }
    }
    GBAR();

    for (int t = 0; t < 32; ++t){
      const int p = t & 1;
      const u16* note_p = noteb + (size_t)p*NOTE_PAR;
      u16*       note_n = noteb + (size_t)(p ^ 1)*NOTE_PAR;
      const u16* hd0_p = hd0b + (size_t)p*HD_PAR;
      u16*       hd0_n = hd0b + (size_t)(p ^ 1)*HD_PAR;
      const u16* hd1_p = hd1b + (size_t)p*HD_PAR;
      u16*       hd1_n = hd1b + (size_t)(p ^ 1)*HD_PAR;

      /* phase 1: d0 = Wih.note + g0e (+ shadow Whh from prev phase) */
      if (is_d0){
        f32x4 a0, a1;
        if (t == 0){
          a0 = (f32x4){0.f,0.f,0.f,0.f}; a1 = a0;
          mm_lds<13,32,true>(Wd0 + (size_t)rr*KD0 + q*8, 16*KD0,
                             note_p + lofs, hd0_p + lofs, a0, a1);
        } else {
          a0 = sh0; a1 = sh1;
          mm_lds<13,0,true>(Wd0 + (size_t)rr*KD0 + q*8, 16*KD0,
                            note_p + lofs, note_p + lofs, a0, a1);
        }
#pragma unroll
        for (int i = 0; i < 4; ++i){
          g_sc[(m0 + q*4 + i)*33 + rr]      = a0[i];
          g_sc[(m0 + q*4 + i)*33 + 16 + rr] = a1[i];
        }
        __syncthreads();
        cell_pw(g_sc, g0e, nullptr, cst0, packU32, tid);
        __syncthreads();
        if (tid < 64){
          u32x4 v = *(const u32x4*)&packU32[tid*4];
          gst4(hd0_n + ((size_t)wg*64 + tid)*8, v);
        }
      }
      GBAR();

      /* phase 2: d1 = Wih_d1.hd0_n (+ shadow)  ||  d0 shadow = Whh_d0.hd0_n */
      if (!is_d0){
        f32x4 a0, a1;
        if (t == 0){
          a0 = (f32x4){0.f,0.f,0.f,0.f}; a1 = a0;
          mm_lds<32,32,true>(Wd1 + (size_t)rr*KD1 + q*8, 16*KD1,
                             hd0_n + lofs, hd1_p + lofs, a0, a1);
        } else {
          a0 = t10; a1 = t11;
          mm_lds<32,0,true>(Wd1 + (size_t)rr*KD1 + q*8, 16*KD1,
                            hd0_n + lofs, hd0_n + lofs, a0, a1);
        }
#pragma unroll
        for (int i = 0; i < 4; ++i){
          g_sc[(m0 + q*4 + i)*33 + rr]      = a0[i];
          g_sc[(m0 + q*4 + i)*33 + 16 + rr] = a1[i];
        }
        __syncthreads();
        cell_pw(g_sc, nullptr, bd1, cst1, packU32, tid);
        __syncthreads();
        if (tid < 64){
          u32x4 v = *(const u32x4*)&packU32[tid*4];
          gst4(hd1_n + ((size_t)(wg - 128)*64 + tid)*8, v);
        }
      } else {
        sh0 = (f32x4){0.f,0.f,0.f,0.f}; sh1 = sh0;
        mm_lds<32,0,true>(Wd0 + (size_t)rr*KD0 + 416 + q*8, 16*KD0,
                          hd0_n + lofs, hd0_n + lofs, sh0, sh1);
      }
      GBAR();

      /* phase 3: proj (25 WGs)  ||  d1 shadow = Whh_d1.hd1_n */
      if (wg < 25){
        f32x4 a0 = {0.f,0.f,0.f,0.f}, a1;
        mm_lds<32,0,false>(Wpj + (size_t)rr*KPROJ + q*8, 0,
                           hd1_n + lofs, hd1_n + lofs, a0, a1);
        const int row = 16*wg + rr;
        const int seq = s*32 + t;
        const float bias = bpj[rr];
#pragma unroll
        for (int i = 0; i < 4; ++i){
          const int brow = m0 + q*4 + i;
          const float nv = tanh_(a0[i] + bias);
          if (row < 389) P.out[((size_t)brow*512 + seq)*389 + row] = nv;
          pack16[brow*16 + rr] = f2bf(nv);
        }
        __syncthreads();
        if (tid < 64){
          u32x4 v0 = *(const u32x4*)&packU32[tid*8];
          u32x4 v1 = *(const u32x4*)&packU32[tid*8 + 4];
          gst4(note_n + ((size_t)(2*wg)*64 + tid)*8, v0);
          gst4(note_n + ((size_t)(2*wg + 1)*64 + tid)*8, v1);
        }
      }
      if (!is_d0){
        t10 = (f32x4){0.f,0.f,0.f,0.f}; t11 = t10;
        mm_lds<32,0,true>(Wd1 + (size_t)rr*KD1 + 1024 + q*8, 16*KD1,
                          hd1_n + lofs, hd1_n + lofs, t10, t11);
      }
      GBAR();
    }
  }
#undef GBAR
}

extern "C" void kernel_launch(void* const* d_in, const int* in_sizes, int n_in,
                              void* d_out, int out_size, void* d_ws, size_t ws_size,
                              hipStream_t stream){
  (void)in_sizes; (void)n_in; (void)out_size;
  if (ws_size < (size_t)WS_END) return;

  Params P;
  P.latent = (const float*)d_in[0];
  P.h0_dec = (const float*)d_in[3];
  P.c0_dec = (const float*)d_in[4];
  P.Wih_c0 = (const float*)d_in[5];  P.Whh_c0 = (const float*)d_in[6];
  P.bih_c0 = (const float*)d_in[7];  P.bhh_c0 = (const float*)d_in[8];
  P.Wih_c1 = (const float*)d_in[9];  P.Whh_c1 = (const float*)d_in[10];
  P.bih_c1 = (const float*)d_in[11]; P.bhh_c1 = (const float*)d_in[12];
  P.Wco    = (const float*)d_in[13]; P.bco    = (const float*)d_in[14];
  P.Wih_d0 = (const float*)d_in[15]; P.Whh_d0 = (const float*)d_in[16];
  P.bih_d0 = (const float*)d_in[17]; P.bhh_d0 = (const float*)d_in[18];
  P.Wih_d1 = (const float*)d_in[19]; P.Whh_d1 = (const float*)d_in[20];
  P.bih_d1 = (const float*)d_in[21]; P.bhh_d1 = (const float*)d_in[22];
  P.Wdo    = (const float*)d_in[23]; P.bdo    = (const float*)d_in[24];
  P.out = (float*)d_out;
  P.ws  = (char*)d_ws;

  hipLaunchKernelGGL(init_kernel, dim3(256), dim3(256), 0, stream,
                     (const float*)d_in[0], (char*)d_ws);

  hipFuncSetAttribute(reinterpret_cast<const void*>(&decoder_kernel),
                      hipFuncAttributeMaxDynamicSharedMemorySize, LDS_BYTES);
  hipLaunchKernelGGL(decoder_kernel, dim3(NWG), dim3(256), LDS_BYTES, stream, P);
}